// Round 6
// baseline (5329.699 us; speedup 1.0000x reference)
//
#include <hip/hip_runtime.h>
#include <math.h>

#define NPTS 4096
#define NBATCH 8
#define TOTAL (NBATCH*NPTS)   // 32768
#define KNN 30

// ---------- helpers ----------
__device__ __forceinline__ unsigned key_xform(float v) {
  unsigned u = __float_as_uint(v);
  return (u & 0x80000000u) ? ~u : (u | 0x80000000u);  // monotonic float->uint
}
__device__ __forceinline__ float key_unxform(unsigned k) {
  unsigned u = (k & 0x80000000u) ? (k ^ 0x80000000u) : ~k;
  return __uint_as_float(u);
}

// ---------- row squared-norms ----------
__global__ void norms_k(const float* __restrict__ X, int rs, int C, float* __restrict__ S) {
  int i = blockIdx.x * 256 + threadIdx.x;
  if (i >= TOTAL) return;
  const float* r = X + (size_t)i * rs;
  float a = 0.f;
  for (int c = 0; c < C; ++c) { float v = r[c]; a = fmaf(v, v, a); }
  S[i] = a;
}

// ---------- distance tile GEMM: D[lr][j] = s_i + s_j - 2*dot ----------
// grid (32 col-tiles, 16 row-tiles), strip of 2048 rows
__global__ __launch_bounds__(256) void dist_k(const float* __restrict__ X, int rs, int C,
    const float* __restrict__ S, int aBase, int bBase, float* __restrict__ D) {
  __shared__ __align__(16) float At[64][128];
  __shared__ __align__(16) float Bt[64][128];
  __shared__ float sA[128], sB[128];
  int tid = threadIdx.x;
  int bx = blockIdx.x, by = blockIdx.y;
  int a0 = aBase + by * 128, b0 = bBase + bx * 128;
  if (tid < 128) sA[tid] = S[a0 + tid];
  else           sB[tid - 128] = S[b0 + tid - 128];
  if ((C & 3) == 0) {
    int nv = 128 * (C >> 2);
    for (int i = tid; i < nv; i += 256) {
      int m = i & 127, kq = i >> 7;
      float4 va = *(const float4*)(X + (size_t)(a0 + m) * rs + kq * 4);
      At[kq*4+0][m] = va.x; At[kq*4+1][m] = va.y; At[kq*4+2][m] = va.z; At[kq*4+3][m] = va.w;
      float4 vb = *(const float4*)(X + (size_t)(b0 + m) * rs + kq * 4);
      Bt[kq*4+0][m] = vb.x; Bt[kq*4+1][m] = vb.y; Bt[kq*4+2][m] = vb.z; Bt[kq*4+3][m] = vb.w;
    }
  } else {
    for (int i = tid; i < 128 * C; i += 256) {
      int m = i & 127, k = i >> 7;
      At[k][m] = X[(size_t)(a0 + m) * rs + k];
      Bt[k][m] = X[(size_t)(b0 + m) * rs + k];
    }
  }
  __syncthreads();
  float acc[8][8] = {};
  int tx = tid & 15, ty = tid >> 4;
  for (int k = 0; k < C; ++k) {
    float av[8], bv[8];
    *(float4*)&av[0] = *(const float4*)&At[k][ty * 8];
    *(float4*)&av[4] = *(const float4*)&At[k][ty * 8 + 4];
    *(float4*)&bv[0] = *(const float4*)&Bt[k][tx * 8];
    *(float4*)&bv[4] = *(const float4*)&Bt[k][tx * 8 + 4];
#pragma unroll
    for (int i = 0; i < 8; ++i)
#pragma unroll
      for (int j = 0; j < 8; ++j) acc[i][j] = fmaf(av[i], bv[j], acc[i][j]);
  }
#pragma unroll
  for (int i = 0; i < 8; ++i) {
    int lr = by * 128 + ty * 8 + i;
    float si = sA[ty * 8 + i];
    float4 o0, o1;
    o0.x = si + sB[tx*8+0] - 2.f * acc[i][0];
    o0.y = si + sB[tx*8+1] - 2.f * acc[i][1];
    o0.z = si + sB[tx*8+2] - 2.f * acc[i][2];
    o0.w = si + sB[tx*8+3] - 2.f * acc[i][3];
    o1.x = si + sB[tx*8+4] - 2.f * acc[i][4];
    o1.y = si + sB[tx*8+5] - 2.f * acc[i][5];
    o1.z = si + sB[tx*8+6] - 2.f * acc[i][6];
    o1.w = si + sB[tx*8+7] - 2.f * acc[i][7];
    float* dp = D + (size_t)lr * NPTS + bx * 128 + tx * 8;
    *(float4*)dp = o0;
    *(float4*)(dp + 4) = o1;
  }
}

// ---------- top-30 smallest per row (1 wave per row) ----------
#define SENTK 0xFFFFFFFFFFFFFFFFull
__global__ __launch_bounds__(64) void topk_k(const float* __restrict__ D, int* __restrict__ IDXo,
                                             int gBase, int bBase) {
  __shared__ __align__(16) float dist[NPTS];
  int lane = threadIdx.x;
  const float* drow = D + (size_t)blockIdx.x * NPTS;
  for (int q = 0; q < 16; ++q)
    ((float4*)dist)[lane + 64 * q] = ((const float4*)drow)[lane + 64 * q];
  __syncthreads();
  unsigned long long k1 = SENTK, k2 = SENTK;
  for (int q = 0; q < 64; ++q) {
    int idx = q * 64 + lane;
    unsigned long long kk = ((unsigned long long)key_xform(dist[idx]) << 32) | (unsigned)idx;
    if (kk < k1) { k2 = k1; k1 = kk; } else if (kk < k2) k2 = kk;
  }
  for (int it = 0; it < KNN; ++it) {
    unsigned long long km = k1;
#pragma unroll
    for (int d = 1; d < 64; d <<= 1) {
      unsigned long long o = __shfl_xor(km, d);
      if (o < km) km = o;
    }
    int widx = (int)(km & 0xFFFFFFFFu);
    if (lane == 0) IDXo[(size_t)(gBase + blockIdx.x) * KNN + it] = bBase + widx;
    if ((widx & 63) == lane) {
      dist[widx] = __builtin_inff();
      if (k2 != SENTK) { k1 = k2; k2 = SENTK; }
      else {
        k1 = SENTK; k2 = SENTK;
        for (int q = 0; q < 64; ++q) {
          int idx = q * 64 + lane;
          unsigned long long kk = ((unsigned long long)key_xform(dist[idx]) << 32) | (unsigned)idx;
          if (kk < k1) { k2 = k1; k1 = kk; } else if (kk < k2) k2 = kk;
        }
      }
    }
  }
}

// ---------- per-point u/v: u = X@(W1a-W1b)+b1, v = X@W1b ----------
__global__ __launch_bounds__(256) void uv_k(const float* __restrict__ X, int rs, int C,
    const float* __restrict__ W1, const float* __restrict__ B1,
    float* __restrict__ U, float* __restrict__ V) {
  __shared__ float wd[64][64];
  __shared__ float wb[64][64];
  __shared__ float xs[4][64];
  int tid = threadIdx.x;
  int c = tid & 63, pl = tid >> 6;
  for (int i = tid; i < C * 64; i += 256) {
    float a = W1[i], b = W1[C * 64 + i];
    wd[i >> 6][i & 63] = a - b;
    wb[i >> 6][i & 63] = b;
  }
  int p0 = blockIdx.x * 4;
  for (int i = tid; i < 4 * C; i += 256)
    xs[i / C][i % C] = X[(size_t)(p0 + i / C) * rs + (i % C)];
  __syncthreads();
  float u = B1[c], v = 0.f;
  for (int k = 0; k < C; ++k) {
    float x = xs[pl][k];
    u = fmaf(x, wd[k][c], u);
    v = fmaf(x, wb[k][c], v);
  }
  int p = p0 + pl;
  U[(size_t)p * 64 + c] = u;
  V[(size_t)p * 64 + c] = v;
}

// ---------- edge conv: F[p][colOut+c] = max_j relu(u_p + v_idx)@W2 + b2 ----------
// block: 8 points (240 edges, padded to 256 rows), 256 threads, 8x8 micro-tile
__global__ __launch_bounds__(256) void edge_k(const float* __restrict__ U, const float* __restrict__ V,
    const float* __restrict__ W2, const float* __restrict__ B2, const int* __restrict__ IDX,
    float* __restrict__ F, int colOut) {
  __shared__ __align__(16) float At[16][260];
  __shared__ __align__(16) float W2s[64][64];
  __shared__ __align__(16) float us[8][64];
  __shared__ int idxs[256];
  __shared__ unsigned om[512];
  int tid = threadIdx.x;
  int p0 = blockIdx.x * 8;
  for (int i = tid; i < 1024; i += 256) ((float4*)W2s)[i] = ((const float4*)W2)[i];
  for (int i = tid; i < 128; i += 256)
    ((float4*)us)[i] = ((const float4*)(U + (size_t)p0 * 64))[i];
  for (int m = tid; m < 256; m += 256)
    idxs[m] = IDX[(size_t)p0 * KNN + (m < 240 ? m : 239)];
  for (int i = tid; i < 512; i += 256) om[i] = 0u;
  __syncthreads();
  float acc[8][8] = {};
  int tx = tid & 7, ty = tid >> 3;
  for (int kc = 0; kc < 4; ++kc) {
    for (int i = tid; i < 1024; i += 256) {
      int m = i >> 2, kq = i & 3;
      int um = m / 30; if (um > 7) um = 7;
      float4 vv = *(const float4*)(V + (size_t)idxs[m] * 64 + kc * 16 + kq * 4);
      float4 uu = *(const float4*)&us[um][kc * 16 + kq * 4];
      At[kq*4+0][m] = fmaxf(uu.x + vv.x, 0.f);
      At[kq*4+1][m] = fmaxf(uu.y + vv.y, 0.f);
      At[kq*4+2][m] = fmaxf(uu.z + vv.z, 0.f);
      At[kq*4+3][m] = fmaxf(uu.w + vv.w, 0.f);
    }
    __syncthreads();
#pragma unroll
    for (int k = 0; k < 16; ++k) {
      float av[8], bv[8];
      *(float4*)&av[0] = *(const float4*)&At[k][ty * 8];
      *(float4*)&av[4] = *(const float4*)&At[k][ty * 8 + 4];
      *(float4*)&bv[0] = *(const float4*)&W2s[kc * 16 + k][tx * 8];
      *(float4*)&bv[4] = *(const float4*)&W2s[kc * 16 + k][tx * 8 + 4];
#pragma unroll
      for (int i = 0; i < 8; ++i)
#pragma unroll
        for (int j = 0; j < 8; ++j) acc[i][j] = fmaf(av[i], bv[j], acc[i][j]);
    }
    __syncthreads();
  }
#pragma unroll
  for (int i = 0; i < 8; ++i) {
    int m = ty * 8 + i;
    if (m < 240) {
      int pt = m / 30;
#pragma unroll
      for (int j = 0; j < 8; ++j)
        atomicMax(&om[pt * 64 + tx * 8 + j], key_xform(acc[i][j]));
    }
  }
  __syncthreads();
  for (int i = tid; i < 512; i += 256) {
    int pt = i >> 6, c = i & 63;
    F[(size_t)(p0 + pt) * 192 + colOut + c] = key_unxform(om[i]) + B2[c];
  }
}

// ---------- generic fp32 GEMM (M,N mult of 128; Kd mult of 16) + bias + relu ----------
__global__ __launch_bounds__(256) void gemm_k(const float* __restrict__ A, const float* __restrict__ B,
    const float* __restrict__ bias, float* __restrict__ C, int M, int N, int Kd, int lda, int doRelu) {
  __shared__ __align__(16) float At[16][132];
  __shared__ __align__(16) float Bs[16][128];
  int tid = threadIdx.x, bx = blockIdx.x, by = blockIdx.y;
  int m0 = by * 128, n0 = bx * 128;
  float acc[8][8] = {};
  int tx = tid & 15, ty = tid >> 4;
  for (int k0 = 0; k0 < Kd; k0 += 16) {
    if (k0) __syncthreads();
    for (int i = tid; i < 512; i += 256) {
      int m = i & 127, kq = i >> 7;
      float4 v = *(const float4*)(A + (size_t)(m0 + m) * lda + k0 + kq * 4);
      At[kq*4+0][m] = v.x; At[kq*4+1][m] = v.y; At[kq*4+2][m] = v.z; At[kq*4+3][m] = v.w;
    }
    for (int i = tid; i < 512; i += 256) {
      int n4 = i & 31, k = i >> 5;
      *(float4*)&Bs[k][n4 * 4] = *(const float4*)(B + (size_t)(k0 + k) * N + n0 + n4 * 4);
    }
    __syncthreads();
#pragma unroll
    for (int k = 0; k < 16; ++k) {
      float av[8], bv[8];
      *(float4*)&av[0] = *(const float4*)&At[k][ty * 8];
      *(float4*)&av[4] = *(const float4*)&At[k][ty * 8 + 4];
      *(float4*)&bv[0] = *(const float4*)&Bs[k][tx * 8];
      *(float4*)&bv[4] = *(const float4*)&Bs[k][tx * 8 + 4];
#pragma unroll
      for (int i = 0; i < 8; ++i)
#pragma unroll
        for (int j = 0; j < 8; ++j) acc[i][j] = fmaf(av[i], bv[j], acc[i][j]);
    }
  }
#pragma unroll
  for (int i = 0; i < 8; ++i) {
    int m = m0 + ty * 8 + i;
    float o[8];
#pragma unroll
    for (int j = 0; j < 8; ++j) {
      float x = acc[i][j] + bias[n0 + tx * 8 + j];
      o[j] = doRelu ? fmaxf(x, 0.f) : x;
    }
    float* cp = C + (size_t)m * N + n0 + tx * 8;
    *(float4*)cp = *(float4*)&o[0];
    *(float4*)(cp + 4) = *(float4*)&o[4];
  }
}

// ---------- final fc (128->13) + log_softmax ----------
__global__ void final_k(const float* __restrict__ H, const float* __restrict__ W4,
                        const float* __restrict__ B4, float* __restrict__ O, int rows) {
  int r = blockIdx.x * 256 + threadIdx.x;
  if (r >= rows) return;
  const float* h = H + (size_t)r * 128;
  float l[13];
#pragma unroll
  for (int c = 0; c < 13; ++c) l[c] = B4[c];
  for (int k = 0; k < 128; ++k) {
    float x = h[k];
#pragma unroll
    for (int c = 0; c < 13; ++c) l[c] = fmaf(x, W4[k * 13 + c], l[c]);
  }
  float mx = l[0];
#pragma unroll
  for (int c = 1; c < 13; ++c) mx = fmaxf(mx, l[c]);
  float s = 0.f;
#pragma unroll
  for (int c = 0; c < 13; ++c) s += expf(l[c] - mx);
  float lse = mx + logf(s);
  float* op = O + (size_t)r * 13;
#pragma unroll
  for (int c = 0; c < 13; ++c) op[c] = l[c] - lse;
}

extern "C" void kernel_launch(void* const* d_in, const int* in_sizes, int n_in,
                              void* d_out, int out_size, void* d_ws, size_t ws_size,
                              hipStream_t stream) {
  const float* P = (const float*)d_in[0];
  const float* W1s[3] = {(const float*)d_in[1], (const float*)d_in[5], (const float*)d_in[9]};
  const float* B1s[3] = {(const float*)d_in[2], (const float*)d_in[6], (const float*)d_in[10]};
  const float* W2s_[3] = {(const float*)d_in[3], (const float*)d_in[7], (const float*)d_in[11]};
  const float* B2s[3] = {(const float*)d_in[4], (const float*)d_in[8], (const float*)d_in[12]};
  const float* MW1 = (const float*)d_in[13]; const float* MB1 = (const float*)d_in[14];
  const float* MW2 = (const float*)d_in[15]; const float* MB2 = (const float*)d_in[16];
  const float* MW3 = (const float*)d_in[17]; const float* MB3 = (const float*)d_in[18];
  const float* MW4 = (const float*)d_in[19]; const float* MB4 = (const float*)d_in[20];

  char* w = (char*)d_ws;
  float* F   = (float*)(w + 0);            // 32768 x 192            [0,   25165824)
  float* S   = (float*)(w + 25165824);     // 32768                  [.., 25296896)
  float* U   = (float*)(w + 25296896);     // 32768 x 64             [.., 33685504)
  float* V   = (float*)(w + 33685504);     // 32768 x 64             [.., 42074112)
  int*   IDX = (int*)  (w + 42074112);     // 32768 x 30             [.., 46006272)
  float* D   = (float*)(w + 46006272);     // 2048 x 4096            [.., 79560704)
  float* T1  = D;                          // 8192 x 1024 (alias D)
  float* T2  = U;                          // 8192 x 256  (alias U, dead after edge phase)
  float* T3  = V;                          // 8192 x 128  (alias V, dead after edge phase)
  (void)ws_size; (void)in_sizes; (void)n_in; (void)out_size;

  for (int l = 0; l < 3; ++l) {
    const float* X = (l == 0) ? P : (F + (l - 1) * 64);
    int rs = (l == 0) ? 6 : 192;
    int C  = (l == 0) ? 6 : 64;
    norms_k<<<TOTAL / 256, 256, 0, stream>>>(X, rs, C, S);
    for (int b = 0; b < NBATCH; ++b) {
      for (int h = 0; h < 2; ++h) {
        int aBase = b * NPTS + h * 2048;
        dist_k<<<dim3(32, 16), 256, 0, stream>>>(X, rs, C, S, aBase, b * NPTS, D);
        topk_k<<<2048, 64, 0, stream>>>(D, IDX, aBase, b * NPTS);
      }
    }
    uv_k<<<TOTAL / 4, 256, 0, stream>>>(X, rs, C, W1s[l], B1s[l], U, V);
    edge_k<<<TOTAL / 8, 256, 0, stream>>>(U, V, W2s_[l], B2s[l], IDX, F, l * 64);
  }
  float* OUT = (float*)d_out;
  for (int ch = 0; ch < 4; ++ch) {
    const float* A0 = F + (size_t)ch * 8192 * 192;
    gemm_k<<<dim3(8, 64), 256, 0, stream>>>(A0, MW1, MB1, T1, 8192, 1024, 192, 192, 1);
    gemm_k<<<dim3(2, 64), 256, 0, stream>>>(T1, MW2, MB2, T2, 8192, 256, 1024, 1024, 1);
    gemm_k<<<dim3(1, 64), 256, 0, stream>>>(T2, MW3, MB3, T3, 8192, 128, 256, 256, 1);
    final_k<<<8192 / 256, 256, 0, stream>>>(T3, MW4, MB4, OUT + (size_t)ch * 8192 * 13, 8192);
  }
}

// Round 7
// 4518.776 us; speedup vs baseline: 1.1795x; 1.1795x over previous
//
#include <hip/hip_runtime.h>
#include <math.h>

#define NPTS 4096
#define NBATCH 8
#define TOTAL (NBATCH*NPTS)   // 32768
#define KNN 30

// ---------- helpers ----------
__device__ __forceinline__ unsigned key_xform(float v) {
  unsigned u = __float_as_uint(v);
  return (u & 0x80000000u) ? ~u : (u | 0x80000000u);  // monotonic float->uint
}
__device__ __forceinline__ float key_unxform(unsigned k) {
  unsigned u = (k & 0x80000000u) ? (k ^ 0x80000000u) : ~k;
  return __uint_as_float(u);
}

// ---------- row squared-norms ----------
__global__ void norms_k(const float* __restrict__ X, int rs, int C, float* __restrict__ S) {
  int i = blockIdx.x * 256 + threadIdx.x;
  if (i >= TOTAL) return;
  const float* r = X + (size_t)i * rs;
  float a = 0.f;
  for (int c = 0; c < C; ++c) { float v = r[c]; a = fmaf(v, v, a); }
  S[i] = a;
}

// ---------- distance tile GEMM: D[lr][j] = s_i + s_j - 2*dot ----------
// micro-tile split-stride (ty*4 / ty*4+64) => 2-way LDS access = conflict-free
__global__ __launch_bounds__(256) void dist_k(const float* __restrict__ X, int rs, int C,
    const float* __restrict__ S, int aBase, int bBase, float* __restrict__ D) {
  __shared__ __align__(16) float At[64][128];
  __shared__ __align__(16) float Bt[64][128];
  __shared__ float sA[128], sB[128];
  int tid = threadIdx.x;
  int bx = blockIdx.x, by = blockIdx.y;
  int a0 = aBase + by * 128, b0 = bBase + bx * 128;
  if (tid < 128) sA[tid] = S[a0 + tid];
  else           sB[tid - 128] = S[b0 + tid - 128];
  if ((C & 3) == 0) {
    int nv = 128 * (C >> 2);
    for (int i = tid; i < nv; i += 256) {
      int m = i & 127, kq = i >> 7;
      float4 va = *(const float4*)(X + (size_t)(a0 + m) * rs + kq * 4);
      At[kq*4+0][m] = va.x; At[kq*4+1][m] = va.y; At[kq*4+2][m] = va.z; At[kq*4+3][m] = va.w;
      float4 vb = *(const float4*)(X + (size_t)(b0 + m) * rs + kq * 4);
      Bt[kq*4+0][m] = vb.x; Bt[kq*4+1][m] = vb.y; Bt[kq*4+2][m] = vb.z; Bt[kq*4+3][m] = vb.w;
    }
  } else {
    for (int i = tid; i < 128 * C; i += 256) {
      int m = i & 127, k = i >> 7;
      At[k][m] = X[(size_t)(a0 + m) * rs + k];
      Bt[k][m] = X[(size_t)(b0 + m) * rs + k];
    }
  }
  __syncthreads();
  float acc[8][8] = {};
  int tx = tid & 15, ty = tid >> 4;
  for (int k = 0; k < C; ++k) {
    float av[8], bv[8];
    *(float4*)&av[0] = *(const float4*)&At[k][ty * 4];
    *(float4*)&av[4] = *(const float4*)&At[k][ty * 4 + 64];
    *(float4*)&bv[0] = *(const float4*)&Bt[k][tx * 4];
    *(float4*)&bv[4] = *(const float4*)&Bt[k][tx * 4 + 64];
#pragma unroll
    for (int i = 0; i < 8; ++i)
#pragma unroll
      for (int j = 0; j < 8; ++j) acc[i][j] = fmaf(av[i], bv[j], acc[i][j]);
  }
#pragma unroll
  for (int ih = 0; ih < 2; ++ih)
#pragma unroll
  for (int i2 = 0; i2 < 4; ++i2) {
    int i = ih * 4 + i2;
    int row = ty * 4 + i2 + ih * 64;
    int lr = by * 128 + row;
    float si = sA[row];
#pragma unroll
    for (int jh = 0; jh < 2; ++jh) {
      int cb = jh * 64 + tx * 4;
      float4 o;
      o.x = si + sB[cb+0] - 2.f * acc[i][jh*4+0];
      o.y = si + sB[cb+1] - 2.f * acc[i][jh*4+1];
      o.z = si + sB[cb+2] - 2.f * acc[i][jh*4+2];
      o.w = si + sB[cb+3] - 2.f * acc[i][jh*4+3];
      *(float4*)(D + (size_t)lr * NPTS + bx * 128 + cb) = o;
    }
  }
}

// ---------- top-30 smallest per row (1 wave per row) ----------
#define SENTK 0xFFFFFFFFFFFFFFFFull
__global__ __launch_bounds__(64) void topk_k(const float* __restrict__ D, int* __restrict__ IDXo,
                                             int gBase, int bBase) {
  __shared__ __align__(16) float dist[NPTS];
  int lane = threadIdx.x;
  const float* drow = D + (size_t)blockIdx.x * NPTS;
  for (int q = 0; q < 16; ++q)
    ((float4*)dist)[lane + 64 * q] = ((const float4*)drow)[lane + 64 * q];
  __syncthreads();
  unsigned long long k1 = SENTK, k2 = SENTK;
  for (int q = 0; q < 64; ++q) {
    int idx = q * 64 + lane;
    unsigned long long kk = ((unsigned long long)key_xform(dist[idx]) << 32) | (unsigned)idx;
    if (kk < k1) { k2 = k1; k1 = kk; } else if (kk < k2) k2 = kk;
  }
  for (int it = 0; it < KNN; ++it) {
    unsigned long long km = k1;
#pragma unroll
    for (int d = 1; d < 64; d <<= 1) {
      unsigned long long o = __shfl_xor(km, d);
      if (o < km) km = o;
    }
    int widx = (int)(km & 0xFFFFFFFFu);
    if (lane == 0) IDXo[(size_t)(gBase + blockIdx.x) * KNN + it] = bBase + widx;
    if ((widx & 63) == lane) {
      dist[widx] = __builtin_inff();
      if (k2 != SENTK) { k1 = k2; k2 = SENTK; }
      else {
        k1 = SENTK; k2 = SENTK;
        for (int q = 0; q < 64; ++q) {
          int idx = q * 64 + lane;
          unsigned long long kk = ((unsigned long long)key_xform(dist[idx]) << 32) | (unsigned)idx;
          if (kk < k1) { k2 = k1; k1 = kk; } else if (kk < k2) k2 = kk;
        }
      }
    }
  }
}

// ---------- per-point u/v: u = X@(W1a-W1b)+b1, v = X@W1b ----------
__global__ __launch_bounds__(256) void uv_k(const float* __restrict__ X, int rs, int C,
    const float* __restrict__ W1, const float* __restrict__ B1,
    float* __restrict__ U, float* __restrict__ V) {
  __shared__ float wd[64][64];
  __shared__ float wb[64][64];
  __shared__ float xs[4][64];
  int tid = threadIdx.x;
  int c = tid & 63, pl = tid >> 6;
  for (int i = tid; i < C * 64; i += 256) {
    float a = W1[i], b = W1[C * 64 + i];
    wd[i >> 6][i & 63] = a - b;
    wb[i >> 6][i & 63] = b;
  }
  int p0 = blockIdx.x * 4;
  for (int i = tid; i < 4 * C; i += 256)
    xs[i / C][i % C] = X[(size_t)(p0 + i / C) * rs + (i % C)];
  __syncthreads();
  float u = B1[c], v = 0.f;
  for (int k = 0; k < C; ++k) {
    float x = xs[pl][k];
    u = fmaf(x, wd[k][c], u);
    v = fmaf(x, wb[k][c], v);
  }
  int p = p0 + pl;
  U[(size_t)p * 64 + c] = u;
  V[(size_t)p * 64 + c] = v;
}

// ---------- edge conv: F[p][colOut+c] = max_j relu(u_p + v_idx)@W2 + b2 ----------
// micro-tile split-stride: rows {ty*4, ty*4+128}, cols {tx*4, tx*4+32}
__global__ __launch_bounds__(256) void edge_k(const float* __restrict__ U, const float* __restrict__ V,
    const float* __restrict__ W2, const float* __restrict__ B2, const int* __restrict__ IDX,
    float* __restrict__ F, int colOut) {
  __shared__ __align__(16) float At[16][260];
  __shared__ __align__(16) float W2s[64][64];
  __shared__ __align__(16) float us[8][64];
  __shared__ int idxs[256];
  __shared__ unsigned om[512];
  int tid = threadIdx.x;
  int p0 = blockIdx.x * 8;
  for (int i = tid; i < 1024; i += 256) ((float4*)W2s)[i] = ((const float4*)W2)[i];
  for (int i = tid; i < 128; i += 256)
    ((float4*)us)[i] = ((const float4*)(U + (size_t)p0 * 64))[i];
  for (int m = tid; m < 256; m += 256)
    idxs[m] = IDX[(size_t)p0 * KNN + (m < 240 ? m : 239)];
  for (int i = tid; i < 512; i += 256) om[i] = 0u;
  __syncthreads();
  float acc[8][8] = {};
  int tx = tid & 7, ty = tid >> 3;
  for (int kc = 0; kc < 4; ++kc) {
    for (int i = tid; i < 1024; i += 256) {
      int m = i >> 2, kq = i & 3;
      int um = m / 30; if (um > 7) um = 7;
      float4 vv = *(const float4*)(V + (size_t)idxs[m] * 64 + kc * 16 + kq * 4);
      float4 uu = *(const float4*)&us[um][kc * 16 + kq * 4];
      At[kq*4+0][m] = fmaxf(uu.x + vv.x, 0.f);
      At[kq*4+1][m] = fmaxf(uu.y + vv.y, 0.f);
      At[kq*4+2][m] = fmaxf(uu.z + vv.z, 0.f);
      At[kq*4+3][m] = fmaxf(uu.w + vv.w, 0.f);
    }
    __syncthreads();
#pragma unroll
    for (int k = 0; k < 16; ++k) {
      float av[8], bv[8];
      *(float4*)&av[0] = *(const float4*)&At[k][ty * 4];
      *(float4*)&av[4] = *(const float4*)&At[k][ty * 4 + 128];
      *(float4*)&bv[0] = *(const float4*)&W2s[kc * 16 + k][tx * 4];
      *(float4*)&bv[4] = *(const float4*)&W2s[kc * 16 + k][tx * 4 + 32];
#pragma unroll
      for (int i = 0; i < 8; ++i)
#pragma unroll
        for (int j = 0; j < 8; ++j) acc[i][j] = fmaf(av[i], bv[j], acc[i][j]);
    }
    __syncthreads();
  }
#pragma unroll
  for (int ih = 0; ih < 2; ++ih)
#pragma unroll
  for (int i2 = 0; i2 < 4; ++i2) {
    int i = ih * 4 + i2;
    int m = ty * 4 + i2 + ih * 128;
    if (m < 240) {
      int pt = m / 30;
#pragma unroll
      for (int jh = 0; jh < 2; ++jh)
#pragma unroll
      for (int j2 = 0; j2 < 4; ++j2)
        atomicMax(&om[pt * 64 + tx * 4 + j2 + jh * 32], key_xform(acc[i][jh*4+j2]));
    }
  }
  __syncthreads();
  for (int i = tid; i < 512; i += 256) {
    int pt = i >> 6, c = i & 63;
    F[(size_t)(p0 + pt) * 192 + colOut + c] = key_unxform(om[i]) + B2[c];
  }
}

// ---------- generic fp32 GEMM (M,N mult of 128; Kd mult of 16) + bias + relu ----------
// split-stride micro-tile: conflict-free LDS reads
__global__ __launch_bounds__(256) void gemm_k(const float* __restrict__ A, const float* __restrict__ B,
    const float* __restrict__ bias, float* __restrict__ C, int M, int N, int Kd, int lda, int doRelu) {
  __shared__ __align__(16) float At[16][128];
  __shared__ __align__(16) float Bs[16][128];
  int tid = threadIdx.x, bx = blockIdx.x, by = blockIdx.y;
  int m0 = by * 128, n0 = bx * 128;
  float acc[8][8] = {};
  int tx = tid & 15, ty = tid >> 4;
  for (int k0 = 0; k0 < Kd; k0 += 16) {
    if (k0) __syncthreads();
    for (int i = tid; i < 512; i += 256) {
      int m = i & 127, kq = i >> 7;
      float4 v = *(const float4*)(A + (size_t)(m0 + m) * lda + k0 + kq * 4);
      At[kq*4+0][m] = v.x; At[kq*4+1][m] = v.y; At[kq*4+2][m] = v.z; At[kq*4+3][m] = v.w;
    }
    for (int i = tid; i < 512; i += 256) {
      int n4 = i & 31, k = i >> 5;
      *(float4*)&Bs[k][n4 * 4] = *(const float4*)(B + (size_t)(k0 + k) * N + n0 + n4 * 4);
    }
    __syncthreads();
#pragma unroll
    for (int k = 0; k < 16; ++k) {
      float av[8], bv[8];
      *(float4*)&av[0] = *(const float4*)&At[k][ty * 4];
      *(float4*)&av[4] = *(const float4*)&At[k][ty * 4 + 64];
      *(float4*)&bv[0] = *(const float4*)&Bs[k][tx * 4];
      *(float4*)&bv[4] = *(const float4*)&Bs[k][tx * 4 + 64];
#pragma unroll
      for (int i = 0; i < 8; ++i)
#pragma unroll
        for (int j = 0; j < 8; ++j) acc[i][j] = fmaf(av[i], bv[j], acc[i][j]);
    }
  }
#pragma unroll
  for (int ih = 0; ih < 2; ++ih)
#pragma unroll
  for (int i2 = 0; i2 < 4; ++i2) {
    int i = ih * 4 + i2;
    int m = m0 + ty * 4 + i2 + ih * 64;
#pragma unroll
    for (int jh = 0; jh < 2; ++jh) {
      int cb = n0 + jh * 64 + tx * 4;
      float o[4];
#pragma unroll
      for (int j2 = 0; j2 < 4; ++j2) {
        float x = acc[i][jh*4+j2] + bias[cb + j2];
        o[j2] = doRelu ? fmaxf(x, 0.f) : x;
      }
      *(float4*)(C + (size_t)m * N + cb) = *(float4*)&o[0];
    }
  }
}

// ---------- final fc (128->13) + log_softmax ----------
__global__ __launch_bounds__(256) void final_k(const float* __restrict__ H, const float* __restrict__ W4,
                        const float* __restrict__ B4, float* __restrict__ O, int rows) {
  __shared__ float w4s[128 * 13];
  __shared__ float b4s[13];
  int tid = threadIdx.x;
  for (int i = tid; i < 1664; i += 256) w4s[i] = W4[i];
  if (tid < 13) b4s[tid] = B4[tid];
  __syncthreads();
  int r = blockIdx.x * 256 + tid;
  if (r >= rows) return;
  const float* h = H + (size_t)r * 128;
  float l[13];
#pragma unroll
  for (int c = 0; c < 13; ++c) l[c] = b4s[c];
  for (int k4 = 0; k4 < 32; ++k4) {
    float4 hv = *(const float4*)(h + k4 * 4);
#pragma unroll
    for (int q = 0; q < 4; ++q) {
      float x = (q == 0) ? hv.x : (q == 1) ? hv.y : (q == 2) ? hv.z : hv.w;
      int k = k4 * 4 + q;
#pragma unroll
      for (int c = 0; c < 13; ++c) l[c] = fmaf(x, w4s[k * 13 + c], l[c]);
    }
  }
  float mx = l[0];
#pragma unroll
  for (int c = 1; c < 13; ++c) mx = fmaxf(mx, l[c]);
  float s = 0.f;
#pragma unroll
  for (int c = 0; c < 13; ++c) s += expf(l[c] - mx);
  float lse = mx + logf(s);
  float* op = O + (size_t)r * 13;
#pragma unroll
  for (int c = 0; c < 13; ++c) op[c] = l[c] - lse;
}

extern "C" void kernel_launch(void* const* d_in, const int* in_sizes, int n_in,
                              void* d_out, int out_size, void* d_ws, size_t ws_size,
                              hipStream_t stream) {
  const float* P = (const float*)d_in[0];
  const float* W1s[3] = {(const float*)d_in[1], (const float*)d_in[5], (const float*)d_in[9]};
  const float* B1s[3] = {(const float*)d_in[2], (const float*)d_in[6], (const float*)d_in[10]};
  const float* W2s_[3] = {(const float*)d_in[3], (const float*)d_in[7], (const float*)d_in[11]};
  const float* B2s[3] = {(const float*)d_in[4], (const float*)d_in[8], (const float*)d_in[12]};
  const float* MW1 = (const float*)d_in[13]; const float* MB1 = (const float*)d_in[14];
  const float* MW2 = (const float*)d_in[15]; const float* MB2 = (const float*)d_in[16];
  const float* MW3 = (const float*)d_in[17]; const float* MB3 = (const float*)d_in[18];
  const float* MW4 = (const float*)d_in[19]; const float* MB4 = (const float*)d_in[20];

  char* w = (char*)d_ws;
  float* F   = (float*)(w + 0);            // 32768 x 192            [0,   25165824)
  float* S   = (float*)(w + 25165824);     // 32768                  [.., 25296896)
  float* U   = (float*)(w + 25296896);     // 32768 x 64             [.., 33685504)
  float* V   = (float*)(w + 33685504);     // 32768 x 64             [.., 42074112)
  int*   IDX = (int*)  (w + 42074112);     // 32768 x 30             [.., 46006272)
  float* D   = (float*)(w + 46006272);     // 2048 x 4096            [.., 79560704)
  (void)in_sizes; (void)n_in; (void)out_size;

  for (int l = 0; l < 3; ++l) {
    const float* X = (l == 0) ? P : (F + (l - 1) * 64);
    int rs = (l == 0) ? 6 : 192;
    int C  = (l == 0) ? 6 : 64;
    norms_k<<<TOTAL / 256, 256, 0, stream>>>(X, rs, C, S);
    for (int b = 0; b < NBATCH; ++b) {
      for (int h = 0; h < 2; ++h) {
        int aBase = b * NPTS + h * 2048;
        dist_k<<<dim3(32, 16), 256, 0, stream>>>(X, rs, C, S, aBase, b * NPTS, D);
        topk_k<<<2048, 64, 0, stream>>>(D, IDX, aBase, b * NPTS);
      }
    }
    uv_k<<<TOTAL / 4, 256, 0, stream>>>(X, rs, C, W1s[l], B1s[l], U, V);
    edge_k<<<TOTAL / 8, 256, 0, stream>>>(U, V, W2s_[l], B2s[l], IDX, F, l * 64);
  }

  float* OUT = (float*)d_out;
  if (ws_size >= 213778432u) {
    // full-M MLP: T1 aliases D (dead), T3 aliases U+V (dead)
    float* T1 = (float*)(w + 46006272);      // 32768 x 1024  [.., 180224000)
    float* T2 = (float*)(w + 180224000);     // 32768 x 256   [.., 213778432)
    float* T3 = (float*)(w + 25296896);      // 32768 x 128   (alias U+V)
    gemm_k<<<dim3(8, 256), 256, 0, stream>>>(F, MW1, MB1, T1, 32768, 1024, 192, 192, 1);
    gemm_k<<<dim3(2, 256), 256, 0, stream>>>(T1, MW2, MB2, T2, 32768, 256, 1024, 1024, 1);
    gemm_k<<<dim3(1, 256), 256, 0, stream>>>(T2, MW3, MB3, T3, 32768, 128, 256, 256, 1);
    final_k<<<128, 256, 0, stream>>>(T3, MW4, MB4, OUT, 32768);
  } else {
    float* T1 = D;                           // 8192 x 1024 (alias D)
    float* T2 = U;                           // 8192 x 256  (alias U)
    float* T3 = V;                           // 8192 x 128  (alias V)
    for (int ch = 0; ch < 4; ++ch) {
      const float* A0 = F + (size_t)ch * 8192 * 192;
      gemm_k<<<dim3(8, 64), 256, 0, stream>>>(A0, MW1, MB1, T1, 8192, 1024, 192, 192, 1);
      gemm_k<<<dim3(2, 64), 256, 0, stream>>>(T1, MW2, MB2, T2, 8192, 256, 1024, 1024, 1);
      gemm_k<<<dim3(1, 64), 256, 0, stream>>>(T2, MW3, MB3, T3, 8192, 128, 256, 256, 1);
      final_k<<<8192 / 256, 256, 0, stream>>>(T3, MW4, MB4, OUT + (size_t)ch * 8192 * 13, 8192);
    }
  }
}

// Round 8
// 3278.274 us; speedup vs baseline: 1.6258x; 1.3784x over previous
//
#include <hip/hip_runtime.h>
#include <math.h>

#define NPTS 4096
#define NBATCH 8
#define TOTAL (NBATCH*NPTS)   // 32768
#define KNN 30

// ---------- helpers ----------
__device__ __forceinline__ unsigned key_xform(float v) {
  unsigned u = __float_as_uint(v);
  return (u & 0x80000000u) ? ~u : (u | 0x80000000u);  // monotonic float->uint
}
__device__ __forceinline__ float key_unxform(unsigned k) {
  unsigned u = (k & 0x80000000u) ? (k ^ 0x80000000u) : ~k;
  return __uint_as_float(u);
}

// ---------- row squared-norms ----------
__global__ void norms_k(const float* __restrict__ X, int rs, int C, float* __restrict__ S) {
  int i = blockIdx.x * 256 + threadIdx.x;
  if (i >= TOTAL) return;
  const float* r = X + (size_t)i * rs;
  float a = 0.f;
  for (int c = 0; c < C; ++c) { float v = r[c]; a = fmaf(v, v, a); }
  S[i] = a;
}

// ---------- distance tile GEMM: D[localRow][j] = s_i + s_j - 2*dot ----------
// rows rowBase + by*128 .. ; columns within that row's own batch.
// micro-tile split-stride (ty*4 / ty*4+64) => conflict-free LDS
__global__ __launch_bounds__(256) void dist_k(const float* __restrict__ X, int rs, int C,
    const float* __restrict__ S, int rowBase, float* __restrict__ D) {
  __shared__ __align__(16) float At[64][128];
  __shared__ __align__(16) float Bt[64][128];
  __shared__ float sA[128], sB[128];
  int tid = threadIdx.x;
  int bx = blockIdx.x, by = blockIdx.y;
  int gr0 = rowBase + by * 128;            // global row of tile start (batch-uniform tile)
  int batch0 = gr0 >> 12;                  // gr0 / 4096
  int a0 = gr0;
  int b0 = (batch0 << 12) + bx * 128;      // columns stay inside this row's batch
  if (tid < 128) sA[tid] = S[a0 + tid];
  else           sB[tid - 128] = S[b0 + tid - 128];
  if ((C & 3) == 0) {
    int nv = 128 * (C >> 2);
    for (int i = tid; i < nv; i += 256) {
      int m = i & 127, kq = i >> 7;
      float4 va = *(const float4*)(X + (size_t)(a0 + m) * rs + kq * 4);
      At[kq*4+0][m] = va.x; At[kq*4+1][m] = va.y; At[kq*4+2][m] = va.z; At[kq*4+3][m] = va.w;
      float4 vb = *(const float4*)(X + (size_t)(b0 + m) * rs + kq * 4);
      Bt[kq*4+0][m] = vb.x; Bt[kq*4+1][m] = vb.y; Bt[kq*4+2][m] = vb.z; Bt[kq*4+3][m] = vb.w;
    }
  } else {
    for (int i = tid; i < 128 * C; i += 256) {
      int m = i & 127, k = i >> 7;
      At[k][m] = X[(size_t)(a0 + m) * rs + k];
      Bt[k][m] = X[(size_t)(b0 + m) * rs + k];
    }
  }
  __syncthreads();
  float acc[8][8] = {};
  int tx = tid & 15, ty = tid >> 4;
  for (int k = 0; k < C; ++k) {
    float av[8], bv[8];
    *(float4*)&av[0] = *(const float4*)&At[k][ty * 4];
    *(float4*)&av[4] = *(const float4*)&At[k][ty * 4 + 64];
    *(float4*)&bv[0] = *(const float4*)&Bt[k][tx * 4];
    *(float4*)&bv[4] = *(const float4*)&Bt[k][tx * 4 + 64];
#pragma unroll
    for (int i = 0; i < 8; ++i)
#pragma unroll
      for (int j = 0; j < 8; ++j) acc[i][j] = fmaf(av[i], bv[j], acc[i][j]);
  }
#pragma unroll
  for (int ih = 0; ih < 2; ++ih)
#pragma unroll
  for (int i2 = 0; i2 < 4; ++i2) {
    int i = ih * 4 + i2;
    int row = ty * 4 + i2 + ih * 64;
    int lr = by * 128 + row;               // row within D buffer
    float si = sA[row];
#pragma unroll
    for (int jh = 0; jh < 2; ++jh) {
      int cb = jh * 64 + tx * 4;
      float4 o;
      o.x = si + sB[cb+0] - 2.f * acc[i][jh*4+0];
      o.y = si + sB[cb+1] - 2.f * acc[i][jh*4+1];
      o.z = si + sB[cb+2] - 2.f * acc[i][jh*4+2];
      o.w = si + sB[cb+3] - 2.f * acc[i][jh*4+3];
      *(float4*)(D + (size_t)lr * NPTS + bx * 128 + cb) = o;
    }
  }
}

// ---------- top-30 smallest per row (1 wave per row) ----------
#define SENTK 0xFFFFFFFFFFFFFFFFull
__global__ __launch_bounds__(64) void topk_k(const float* __restrict__ D, int* __restrict__ IDXo,
                                             int rowBase) {
  __shared__ __align__(16) float dist[NPTS];
  int lane = threadIdx.x;
  int gr = rowBase + blockIdx.x;           // global row
  int bBase = gr & ~(NPTS - 1);            // batch column base
  const float* drow = D + (size_t)blockIdx.x * NPTS;
  for (int q = 0; q < 16; ++q)
    ((float4*)dist)[lane + 64 * q] = ((const float4*)drow)[lane + 64 * q];
  __syncthreads();
  unsigned long long k1 = SENTK, k2 = SENTK;
  for (int q = 0; q < 64; ++q) {
    int idx = q * 64 + lane;
    unsigned long long kk = ((unsigned long long)key_xform(dist[idx]) << 32) | (unsigned)idx;
    if (kk < k1) { k2 = k1; k1 = kk; } else if (kk < k2) k2 = kk;
  }
  for (int it = 0; it < KNN; ++it) {
    unsigned long long km = k1;
#pragma unroll
    for (int d = 1; d < 64; d <<= 1) {
      unsigned long long o = __shfl_xor(km, d);
      if (o < km) km = o;
    }
    int widx = (int)(km & 0xFFFFFFFFu);
    if (lane == 0) IDXo[(size_t)gr * KNN + it] = bBase + widx;
    if ((widx & 63) == lane) {
      dist[widx] = __builtin_inff();
      if (k2 != SENTK) { k1 = k2; k2 = SENTK; }
      else {
        k1 = SENTK; k2 = SENTK;
        for (int q = 0; q < 64; ++q) {
          int idx = q * 64 + lane;
          unsigned long long kk = ((unsigned long long)key_xform(dist[idx]) << 32) | (unsigned)idx;
          if (kk < k1) { k2 = k1; k1 = kk; } else if (kk < k2) k2 = kk;
        }
      }
    }
  }
}

// ---------- per-point u/v: u = X@(W1a-W1b)+b1, v = X@W1b ----------
__global__ __launch_bounds__(256) void uv_k(const float* __restrict__ X, int rs, int C,
    const float* __restrict__ W1, const float* __restrict__ B1,
    float* __restrict__ U, float* __restrict__ V) {
  __shared__ float wd[64][64];
  __shared__ float wb[64][64];
  __shared__ float xs[4][64];
  int tid = threadIdx.x;
  int c = tid & 63, pl = tid >> 6;
  for (int i = tid; i < C * 64; i += 256) {
    float a = W1[i], b = W1[C * 64 + i];
    wd[i >> 6][i & 63] = a - b;
    wb[i >> 6][i & 63] = b;
  }
  int p0 = blockIdx.x * 4;
  for (int i = tid; i < 4 * C; i += 256)
    xs[i / C][i % C] = X[(size_t)(p0 + i / C) * rs + (i % C)];
  __syncthreads();
  float u = B1[c], v = 0.f;
  for (int k = 0; k < C; ++k) {
    float x = xs[pl][k];
    u = fmaf(x, wd[k][c], u);
    v = fmaf(x, wb[k][c], v);
  }
  int p = p0 + pl;
  U[(size_t)p * 64 + c] = u;
  V[(size_t)p * 64 + c] = v;
}

// ---------- edge conv: F[p][colOut+c] = max_j relu(u_p + v_idx)@W2 + b2 ----------
__global__ __launch_bounds__(256) void edge_k(const float* __restrict__ U, const float* __restrict__ V,
    const float* __restrict__ W2, const float* __restrict__ B2, const int* __restrict__ IDX,
    float* __restrict__ F, int colOut) {
  __shared__ __align__(16) float At[16][260];
  __shared__ __align__(16) float W2s[64][64];
  __shared__ __align__(16) float us[8][64];
  __shared__ int idxs[256];
  __shared__ unsigned om[512];
  int tid = threadIdx.x;
  int p0 = blockIdx.x * 8;
  for (int i = tid; i < 1024; i += 256) ((float4*)W2s)[i] = ((const float4*)W2)[i];
  for (int i = tid; i < 128; i += 256)
    ((float4*)us)[i] = ((const float4*)(U + (size_t)p0 * 64))[i];
  for (int m = tid; m < 256; m += 256)
    idxs[m] = IDX[(size_t)p0 * KNN + (m < 240 ? m : 239)];
  for (int i = tid; i < 512; i += 256) om[i] = 0u;
  __syncthreads();
  float acc[8][8] = {};
  int tx = tid & 7, ty = tid >> 3;
  for (int kc = 0; kc < 4; ++kc) {
    for (int i = tid; i < 1024; i += 256) {
      int m = i >> 2, kq = i & 3;
      int um = m / 30; if (um > 7) um = 7;
      float4 vv = *(const float4*)(V + (size_t)idxs[m] * 64 + kc * 16 + kq * 4);
      float4 uu = *(const float4*)&us[um][kc * 16 + kq * 4];
      At[kq*4+0][m] = fmaxf(uu.x + vv.x, 0.f);
      At[kq*4+1][m] = fmaxf(uu.y + vv.y, 0.f);
      At[kq*4+2][m] = fmaxf(uu.z + vv.z, 0.f);
      At[kq*4+3][m] = fmaxf(uu.w + vv.w, 0.f);
    }
    __syncthreads();
#pragma unroll
    for (int k = 0; k < 16; ++k) {
      float av[8], bv[8];
      *(float4*)&av[0] = *(const float4*)&At[k][ty * 4];
      *(float4*)&av[4] = *(const float4*)&At[k][ty * 4 + 128];
      *(float4*)&bv[0] = *(const float4*)&W2s[kc * 16 + k][tx * 4];
      *(float4*)&bv[4] = *(const float4*)&W2s[kc * 16 + k][tx * 4 + 32];
#pragma unroll
      for (int i = 0; i < 8; ++i)
#pragma unroll
        for (int j = 0; j < 8; ++j) acc[i][j] = fmaf(av[i], bv[j], acc[i][j]);
    }
    __syncthreads();
  }
#pragma unroll
  for (int ih = 0; ih < 2; ++ih)
#pragma unroll
  for (int i2 = 0; i2 < 4; ++i2) {
    int i = ih * 4 + i2;
    int m = ty * 4 + i2 + ih * 128;
    if (m < 240) {
      int pt = m / 30;
#pragma unroll
      for (int jh = 0; jh < 2; ++jh)
#pragma unroll
      for (int j2 = 0; j2 < 4; ++j2)
        atomicMax(&om[pt * 64 + tx * 4 + j2 + jh * 32], key_xform(acc[i][jh*4+j2]));
    }
  }
  __syncthreads();
  for (int i = tid; i < 512; i += 256) {
    int pt = i >> 6, c = i & 63;
    F[(size_t)(p0 + pt) * 192 + colOut + c] = key_unxform(om[i]) + B2[c];
  }
}

// ---------- generic fp32 GEMM (M,N mult of 128; Kd mult of 16) + bias + relu ----------
__global__ __launch_bounds__(256) void gemm_k(const float* __restrict__ A, const float* __restrict__ B,
    const float* __restrict__ bias, float* __restrict__ C, int M, int N, int Kd, int lda, int doRelu) {
  __shared__ __align__(16) float At[16][128];
  __shared__ __align__(16) float Bs[16][128];
  int tid = threadIdx.x, bx = blockIdx.x, by = blockIdx.y;
  int m0 = by * 128, n0 = bx * 128;
  float acc[8][8] = {};
  int tx = tid & 15, ty = tid >> 4;
  for (int k0 = 0; k0 < Kd; k0 += 16) {
    if (k0) __syncthreads();
    for (int i = tid; i < 512; i += 256) {
      int m = i & 127, kq = i >> 7;
      float4 v = *(const float4*)(A + (size_t)(m0 + m) * lda + k0 + kq * 4);
      At[kq*4+0][m] = v.x; At[kq*4+1][m] = v.y; At[kq*4+2][m] = v.z; At[kq*4+3][m] = v.w;
    }
    for (int i = tid; i < 512; i += 256) {
      int n4 = i & 31, k = i >> 5;
      *(float4*)&Bs[k][n4 * 4] = *(const float4*)(B + (size_t)(k0 + k) * N + n0 + n4 * 4);
    }
    __syncthreads();
#pragma unroll
    for (int k = 0; k < 16; ++k) {
      float av[8], bv[8];
      *(float4*)&av[0] = *(const float4*)&At[k][ty * 4];
      *(float4*)&av[4] = *(const float4*)&At[k][ty * 4 + 64];
      *(float4*)&bv[0] = *(const float4*)&Bs[k][tx * 4];
      *(float4*)&bv[4] = *(const float4*)&Bs[k][tx * 4 + 64];
#pragma unroll
      for (int i = 0; i < 8; ++i)
#pragma unroll
        for (int j = 0; j < 8; ++j) acc[i][j] = fmaf(av[i], bv[j], acc[i][j]);
    }
  }
#pragma unroll
  for (int ih = 0; ih < 2; ++ih)
#pragma unroll
  for (int i2 = 0; i2 < 4; ++i2) {
    int i = ih * 4 + i2;
    int m = m0 + ty * 4 + i2 + ih * 64;
#pragma unroll
    for (int jh = 0; jh < 2; ++jh) {
      int cb = n0 + jh * 64 + tx * 4;
      float o[4];
#pragma unroll
      for (int j2 = 0; j2 < 4; ++j2) {
        float x = acc[i][jh*4+j2] + bias[cb + j2];
        o[j2] = doRelu ? fmaxf(x, 0.f) : x;
      }
      *(float4*)(C + (size_t)m * N + cb) = *(float4*)&o[0];
    }
  }
}

// ---------- final fc (128->13) + log_softmax ----------
__global__ __launch_bounds__(256) void final_k(const float* __restrict__ H, const float* __restrict__ W4,
                        const float* __restrict__ B4, float* __restrict__ O, int rows) {
  __shared__ float w4s[128 * 13];
  __shared__ float b4s[13];
  int tid = threadIdx.x;
  for (int i = tid; i < 1664; i += 256) w4s[i] = W4[i];
  if (tid < 13) b4s[tid] = B4[tid];
  __syncthreads();
  int r = blockIdx.x * 256 + tid;
  if (r >= rows) return;
  const float* h = H + (size_t)r * 128;
  float l[13];
#pragma unroll
  for (int c = 0; c < 13; ++c) l[c] = b4s[c];
  for (int k4 = 0; k4 < 32; ++k4) {
    float4 hv = *(const float4*)(h + k4 * 4);
#pragma unroll
    for (int q = 0; q < 4; ++q) {
      float x = (q == 0) ? hv.x : (q == 1) ? hv.y : (q == 2) ? hv.z : hv.w;
      int k = k4 * 4 + q;
#pragma unroll
      for (int c = 0; c < 13; ++c) l[c] = fmaf(x, w4s[k * 13 + c], l[c]);
    }
  }
  float mx = l[0];
#pragma unroll
  for (int c = 1; c < 13; ++c) mx = fmaxf(mx, l[c]);
  float s = 0.f;
#pragma unroll
  for (int c = 0; c < 13; ++c) s += expf(l[c] - mx);
  float lse = mx + logf(s);
  float* op = O + (size_t)r * 13;
#pragma unroll
  for (int c = 0; c < 13; ++c) op[c] = l[c] - lse;
}

extern "C" void kernel_launch(void* const* d_in, const int* in_sizes, int n_in,
                              void* d_out, int out_size, void* d_ws, size_t ws_size,
                              hipStream_t stream) {
  const float* P = (const float*)d_in[0];
  const float* W1s[3] = {(const float*)d_in[1], (const float*)d_in[5], (const float*)d_in[9]};
  const float* B1s[3] = {(const float*)d_in[2], (const float*)d_in[6], (const float*)d_in[10]};
  const float* W2s_[3] = {(const float*)d_in[3], (const float*)d_in[7], (const float*)d_in[11]};
  const float* B2s[3] = {(const float*)d_in[4], (const float*)d_in[8], (const float*)d_in[12]};
  const float* MW1 = (const float*)d_in[13]; const float* MB1 = (const float*)d_in[14];
  const float* MW2 = (const float*)d_in[15]; const float* MB2 = (const float*)d_in[16];
  const float* MW3 = (const float*)d_in[17]; const float* MB3 = (const float*)d_in[18];
  const float* MW4 = (const float*)d_in[19]; const float* MB4 = (const float*)d_in[20];

  char* w = (char*)d_ws;
  float* F   = (float*)(w + 0);            // 32768 x 192            [0,   25165824)
  float* S   = (float*)(w + 25165824);     // 32768                  [.., 25296896)
  float* U   = (float*)(w + 25296896);     // 32768 x 64             [.., 33685504)
  float* V   = (float*)(w + 33685504);     // 32768 x 64             [.., 42074112)
  int*   IDX = (int*)  (w + 42074112);     // 32768 x 30             [.., 46006272)
  float* D   = (float*)(w + 46006272);     // big: 8192 x 4096 (134MB) / small: 2048 x 4096
  (void)in_sizes; (void)n_in; (void)out_size;

  bool bigWS = (ws_size >= 213778432u);    // proven available in round 7 run

  for (int l = 0; l < 3; ++l) {
    const float* X = (l == 0) ? P : (F + (l - 1) * 64);
    int rs = (l == 0) ? 6 : 192;
    int C  = (l == 0) ? 6 : 64;
    norms_k<<<TOTAL / 256, 256, 0, stream>>>(X, rs, C, S);
    if (bigWS) {
      for (int g = 0; g < 4; ++g) {        // 8192 rows (2 batches) per pair
        dist_k<<<dim3(32, 64), 256, 0, stream>>>(X, rs, C, S, g * 8192, D);
        topk_k<<<8192, 64, 0, stream>>>(D, IDX, g * 8192);
      }
    } else {
      for (int g = 0; g < 16; ++g) {       // 2048-row strips
        dist_k<<<dim3(32, 16), 256, 0, stream>>>(X, rs, C, S, g * 2048, D);
        topk_k<<<2048, 64, 0, stream>>>(D, IDX, g * 2048);
      }
    }
    uv_k<<<TOTAL / 4, 256, 0, stream>>>(X, rs, C, W1s[l], B1s[l], U, V);
    edge_k<<<TOTAL / 8, 256, 0, stream>>>(U, V, W2s_[l], B2s[l], IDX, F, l * 64);
  }

  float* OUT = (float*)d_out;
  if (bigWS) {
    // full-M MLP: T1 aliases D (dead), T3 aliases U+V (dead)
    float* T1 = (float*)(w + 46006272);      // 32768 x 1024  [.., 180224000)
    float* T2 = (float*)(w + 180224000);     // 32768 x 256   [.., 213754432)
    float* T3 = (float*)(w + 25296896);      // 32768 x 128   (alias U+V)
    gemm_k<<<dim3(8, 256), 256, 0, stream>>>(F, MW1, MB1, T1, 32768, 1024, 192, 192, 1);
    gemm_k<<<dim3(2, 256), 256, 0, stream>>>(T1, MW2, MB2, T2, 32768, 256, 1024, 1024, 1);
    gemm_k<<<dim3(1, 256), 256, 0, stream>>>(T2, MW3, MB3, T3, 32768, 128, 256, 256, 1);
    final_k<<<128, 256, 0, stream>>>(T3, MW4, MB4, OUT, 32768);
  } else {
    float* T1 = D;                           // 8192 x 1024 (alias D)
    float* T2 = U;                           // 8192 x 256  (alias U)
    float* T3 = V;                           // 8192 x 128  (alias V)
    for (int ch = 0; ch < 4; ++ch) {
      const float* A0 = F + (size_t)ch * 8192 * 192;
      gemm_k<<<dim3(8, 64), 256, 0, stream>>>(A0, MW1, MB1, T1, 8192, 1024, 192, 192, 1);
      gemm_k<<<dim3(2, 64), 256, 0, stream>>>(T1, MW2, MB2, T2, 8192, 256, 1024, 1024, 1);
      gemm_k<<<dim3(1, 64), 256, 0, stream>>>(T2, MW3, MB3, T3, 8192, 128, 256, 256, 1);
      final_k<<<8192 / 256, 256, 0, stream>>>(T3, MW4, MB4, OUT + (size_t)ch * 8192 * 13, 8192);
    }
  }
}

// Round 11
// 3234.027 us; speedup vs baseline: 1.6480x; 1.0137x over previous
//
#include <hip/hip_runtime.h>
#include <math.h>

#define NPTS 4096
#define NBATCH 8
#define TOTAL (NBATCH*NPTS)   // 32768
#define KNN 30

// ---------- helpers ----------
__device__ __forceinline__ unsigned key_xform(float v) {
  unsigned u = __float_as_uint(v);
  return (u & 0x80000000u) ? ~u : (u | 0x80000000u);  // monotonic float->uint
}
__device__ __forceinline__ float key_unxform(unsigned k) {
  unsigned u = (k & 0x80000000u) ? (k ^ 0x80000000u) : ~k;
  return __uint_as_float(u);
}

// ---------- row squared-norms ----------
__global__ void norms_k(const float* __restrict__ X, int rs, int C, float* __restrict__ S) {
  int i = blockIdx.x * 256 + threadIdx.x;
  if (i >= TOTAL) return;
  const float* r = X + (size_t)i * rs;
  float a = 0.f;
  if ((C & 3) == 0) {
    for (int c4 = 0; c4 < (C >> 2); ++c4) {
      float4 v = *(const float4*)(r + c4 * 4);
      a = fmaf(v.x, v.x, a); a = fmaf(v.y, v.y, a);
      a = fmaf(v.z, v.z, a); a = fmaf(v.w, v.w, a);
    }
  } else {
    for (int c = 0; c < C; ++c) { float v = r[c]; a = fmaf(v, v, a); }
  }
  S[i] = a;
}

// ---------- distance tile GEMM: D[localRow][j] = s_i + s_j - 2*dot ----------
__global__ __launch_bounds__(256) void dist_k(const float* __restrict__ X, int rs, int C,
    const float* __restrict__ S, int rowBase, float* __restrict__ D) {
  __shared__ __align__(16) float At[64][128];
  __shared__ __align__(16) float Bt[64][128];
  __shared__ float sA[128], sB[128];
  int tid = threadIdx.x;
  int bx = blockIdx.x, by = blockIdx.y;
  int gr0 = rowBase + by * 128;            // global row of tile start (batch-uniform tile)
  int batch0 = gr0 >> 12;                  // gr0 / 4096
  int a0 = gr0;
  int b0 = (batch0 << 12) + bx * 128;      // columns stay inside this row's batch
  if (tid < 128) sA[tid] = S[a0 + tid];
  else           sB[tid - 128] = S[b0 + tid - 128];
  if ((C & 3) == 0) {
    int nv = 128 * (C >> 2);
    for (int i = tid; i < nv; i += 256) {
      int m = i & 127, kq = i >> 7;
      float4 va = *(const float4*)(X + (size_t)(a0 + m) * rs + kq * 4);
      At[kq*4+0][m] = va.x; At[kq*4+1][m] = va.y; At[kq*4+2][m] = va.z; At[kq*4+3][m] = va.w;
      float4 vb = *(const float4*)(X + (size_t)(b0 + m) * rs + kq * 4);
      Bt[kq*4+0][m] = vb.x; Bt[kq*4+1][m] = vb.y; Bt[kq*4+2][m] = vb.z; Bt[kq*4+3][m] = vb.w;
    }
  } else {
    for (int i = tid; i < 128 * C; i += 256) {
      int m = i & 127, k = i >> 7;
      At[k][m] = X[(size_t)(a0 + m) * rs + k];
      Bt[k][m] = X[(size_t)(b0 + m) * rs + k];
    }
  }
  __syncthreads();
  float acc[8][8] = {};
  int tx = tid & 15, ty = tid >> 4;
  for (int k = 0; k < C; ++k) {
    float av[8], bv[8];
    *(float4*)&av[0] = *(const float4*)&At[k][ty * 4];
    *(float4*)&av[4] = *(const float4*)&At[k][ty * 4 + 64];
    *(float4*)&bv[0] = *(const float4*)&Bt[k][tx * 4];
    *(float4*)&bv[4] = *(const float4*)&Bt[k][tx * 4 + 64];
#pragma unroll
    for (int i = 0; i < 8; ++i)
#pragma unroll
      for (int j = 0; j < 8; ++j) acc[i][j] = fmaf(av[i], bv[j], acc[i][j]);
  }
#pragma unroll
  for (int ih = 0; ih < 2; ++ih)
#pragma unroll
  for (int i2 = 0; i2 < 4; ++i2) {
    int i = ih * 4 + i2;
    int row = ty * 4 + i2 + ih * 64;
    int lr = by * 128 + row;               // row within D buffer
    float si = sA[row];
#pragma unroll
    for (int jh = 0; jh < 2; ++jh) {
      int cb = jh * 64 + tx * 4;
      float4 o;
      o.x = si + sB[cb+0] - 2.f * acc[i][jh*4+0];
      o.y = si + sB[cb+1] - 2.f * acc[i][jh*4+1];
      o.z = si + sB[cb+2] - 2.f * acc[i][jh*4+2];
      o.w = si + sB[cb+3] - 2.f * acc[i][jh*4+3];
      *(float4*)(D + (size_t)lr * NPTS + bx * 128 + cb) = o;
    }
  }
}

// ---------- top-30 smallest per row: register-resident, 1 wave per row ----------
// Selections emerge in strictly increasing packed-key order, so "removal" ==
// "ignore keys <= last selected". No LDS, no mutation; rescans are register loops.
#define SENTK 0xFFFFFFFFFFFFFFFFull
__global__ __launch_bounds__(64) void topk_k(const float* __restrict__ D, int* __restrict__ IDXo,
                                             int rowBase) {
  int lane = threadIdx.x;
  int gr = rowBase + blockIdx.x;           // global row
  int bBase = gr & ~(NPTS - 1);            // batch column base
  const float* drow = D + (size_t)blockIdx.x * NPTS;
  float4 dv[16];
#pragma unroll
  for (int q = 0; q < 16; ++q) dv[q] = ((const float4*)drow)[lane + 64 * q];
  // element (q,r) has global index 4*(lane + 64q) + r; owner lane = (idx>>2)&63
  unsigned long long k1 = SENTK, k2 = SENTK;
#pragma unroll
  for (int q = 0; q < 16; ++q) {
#pragma unroll
    for (int r = 0; r < 4; ++r) {
      float d = (r == 0) ? dv[q].x : (r == 1) ? dv[q].y : (r == 2) ? dv[q].z : dv[q].w;
      unsigned idx = 4u * (lane + 64u * q) + r;
      unsigned long long kk = ((unsigned long long)key_xform(d) << 32) | idx;
      if (kk < k1) { k2 = k1; k1 = kk; } else if (kk < k2) k2 = kk;
    }
  }
  for (int it = 0; it < KNN; ++it) {
    unsigned long long km = k1;
#pragma unroll
    for (int d = 1; d < 64; d <<= 1) {
      unsigned long long o = __shfl_xor(km, d);
      if (o < km) km = o;
    }
    unsigned widx = (unsigned)(km & 0xFFFFFFFFu);
    if (lane == 0) IDXo[(size_t)gr * KNN + it] = bBase + (int)widx;
    if (((widx >> 2) & 63u) == (unsigned)lane) {
      // my k1 was selected; k2 (if present) is my next candidate (keys unique)
      if (k2 != SENTK) { k1 = k2; k2 = SENTK; }
      else {
        k1 = SENTK; k2 = SENTK;
#pragma unroll
        for (int q = 0; q < 16; ++q) {
#pragma unroll
          for (int r = 0; r < 4; ++r) {
            float d = (r == 0) ? dv[q].x : (r == 1) ? dv[q].y : (r == 2) ? dv[q].z : dv[q].w;
            unsigned idx = 4u * (lane + 64u * q) + r;
            unsigned long long kk = ((unsigned long long)key_xform(d) << 32) | idx;
            if (kk > km) {
              if (kk < k1) { k2 = k1; k1 = kk; } else if (kk < k2) k2 = kk;
            }
          }
        }
      }
    }
  }
}

// ---------- per-point u/v: u = X@(W1a-W1b)+b1, v = X@W1b ----------
__global__ __launch_bounds__(256) void uv_k(const float* __restrict__ X, int rs, int C,
    const float* __restrict__ W1, const float* __restrict__ B1,
    float* __restrict__ U, float* __restrict__ V) {
  __shared__ float wd[64][64];
  __shared__ float wb[64][64];
  __shared__ float xs[4][64];
  int tid = threadIdx.x;
  int c = tid & 63, pl = tid >> 6;
  for (int i = tid; i < C * 64; i += 256) {
    float a = W1[i], b = W1[C * 64 + i];
    wd[i >> 6][i & 63] = a - b;
    wb[i >> 6][i & 63] = b;
  }
  int p0 = blockIdx.x * 4;
  for (int i = tid; i < 4 * C; i += 256)
    xs[i / C][i % C] = X[(size_t)(p0 + i / C) * rs + (i % C)];
  __syncthreads();
  float u = B1[c], v = 0.f;
  for (int k = 0; k < C; ++k) {
    float x = xs[pl][k];
    u = fmaf(x, wd[k][c], u);
    v = fmaf(x, wb[k][c], v);
  }
  int p = p0 + pl;
  U[(size_t)p * 64 + c] = u;
  V[(size_t)p * 64 + c] = v;
}

// ---------- edge conv: F[p][colOut+c] = max_j relu(u_p + v_idx)@W2 + b2 ----------
// epilogue: per-thread pre-max over same-pt row runs -> ~4x fewer LDS atomics
__global__ __launch_bounds__(256) void edge_k(const float* __restrict__ U, const float* __restrict__ V,
    const float* __restrict__ W2, const float* __restrict__ B2, const int* __restrict__ IDX,
    float* __restrict__ F, int colOut) {
  __shared__ __align__(16) float At[16][260];
  __shared__ __align__(16) float W2s[64][64];
  __shared__ __align__(16) float us[8][64];
  __shared__ int idxs[256];
  __shared__ unsigned om[512];
  int tid = threadIdx.x;
  int p0 = blockIdx.x * 8;
  for (int i = tid; i < 1024; i += 256) ((float4*)W2s)[i] = ((const float4*)W2)[i];
  for (int i = tid; i < 128; i += 256)
    ((float4*)us)[i] = ((const float4*)(U + (size_t)p0 * 64))[i];
  for (int m = tid; m < 256; m += 256)
    idxs[m] = IDX[(size_t)p0 * KNN + (m < 240 ? m : 239)];
  for (int i = tid; i < 512; i += 256) om[i] = 0u;
  __syncthreads();
  float acc[8][8] = {};
  int tx = tid & 7, ty = tid >> 3;
  for (int kc = 0; kc < 4; ++kc) {
    for (int i = tid; i < 1024; i += 256) {
      int m = i >> 2, kq = i & 3;
      int um = m / 30; if (um > 7) um = 7;
      float4 vv = *(const float4*)(V + (size_t)idxs[m] * 64 + kc * 16 + kq * 4);
      float4 uu = *(const float4*)&us[um][kc * 16 + kq * 4];
      At[kq*4+0][m] = fmaxf(uu.x + vv.x, 0.f);
      At[kq*4+1][m] = fmaxf(uu.y + vv.y, 0.f);
      At[kq*4+2][m] = fmaxf(uu.z + vv.z, 0.f);
      At[kq*4+3][m] = fmaxf(uu.w + vv.w, 0.f);
    }
    __syncthreads();
#pragma unroll
    for (int k = 0; k < 16; ++k) {
      float av[8], bv[8];
      *(float4*)&av[0] = *(const float4*)&At[k][ty * 4];
      *(float4*)&av[4] = *(const float4*)&At[k][ty * 4 + 128];
      *(float4*)&bv[0] = *(const float4*)&W2s[kc * 16 + k][tx * 4];
      *(float4*)&bv[4] = *(const float4*)&W2s[kc * 16 + k][tx * 4 + 32];
#pragma unroll
      for (int i = 0; i < 8; ++i)
#pragma unroll
        for (int j = 0; j < 8; ++j) acc[i][j] = fmaf(av[i], bv[j], acc[i][j]);
    }
    __syncthreads();
  }
#pragma unroll
  for (int ih = 0; ih < 2; ++ih) {
    int mbase = ty * 4 + ih * 128;
    if (mbase >= 240) continue;            // 4-aligned padding groups
    int ptA = mbase / 30;
    int ptB = (mbase + 3) / 30;
    int split = (ptB > ptA) ? (ptB * 30 - mbase) : 4;   // i2 < split -> ptA
    float mx[8];
#pragma unroll
    for (int j = 0; j < 8; ++j) mx[j] = acc[ih*4+0][j];
#pragma unroll
    for (int i2 = 1; i2 < 4; ++i2) {
      bool flushNow = (i2 == split);
      if (flushNow) {
#pragma unroll
        for (int j = 0; j < 8; ++j)
          atomicMax(&om[ptA * 64 + tx * 4 + (j & 3) + (j >> 2) * 32], key_xform(mx[j]));
#pragma unroll
        for (int j = 0; j < 8; ++j) mx[j] = acc[ih*4+i2][j];
      } else {
#pragma unroll
        for (int j = 0; j < 8; ++j) mx[j] = fmaxf(mx[j], acc[ih*4+i2][j]);
      }
    }
    int ptEnd = (split == 4) ? ptA : ptB;
#pragma unroll
    for (int j = 0; j < 8; ++j)
      atomicMax(&om[ptEnd * 64 + tx * 4 + (j & 3) + (j >> 2) * 32], key_xform(mx[j]));
  }
  __syncthreads();
  for (int i = tid; i < 512; i += 256) {
    int pt = i >> 6, c = i & 63;
    F[(size_t)(p0 + pt) * 192 + colOut + c] = key_unxform(om[i]) + B2[c];
  }
}

// ---------- generic fp32 GEMM (M,N mult of 128; Kd mult of 16) + bias + relu ----------
__global__ __launch_bounds__(256) void gemm_k(const float* __restrict__ A, const float* __restrict__ B,
    const float* __restrict__ bias, float* __restrict__ C, int M, int N, int Kd, int lda, int doRelu) {
  __shared__ __align__(16) float At[16][128];
  __shared__ __align__(16) float Bs[16][128];
  int tid = threadIdx.x, bx = blockIdx.x, by = blockIdx.y;
  int m0 = by * 128, n0 = bx * 128;
  float acc[8][8] = {};
  int tx = tid & 15, ty = tid >> 4;
  for (int k0 = 0; k0 < Kd; k0 += 16) {
    if (k0) __syncthreads();
    for (int i = tid; i < 512; i += 256) {
      int m = i & 127, kq = i >> 7;
      float4 v = *(const float4*)(A + (size_t)(m0 + m) * lda + k0 + kq * 4);
      At[kq*4+0][m] = v.x; At[kq*4+1][m] = v.y; At[kq*4+2][m] = v.z; At[kq*4+3][m] = v.w;
    }
    for (int i = tid; i < 512; i += 256) {
      int n4 = i & 31, k = i >> 5;
      *(float4*)&Bs[k][n4 * 4] = *(const float4*)(B + (size_t)(k0 + k) * N + n0 + n4 * 4);
    }
    __syncthreads();
#pragma unroll
    for (int k = 0; k < 16; ++k) {
      float av[8], bv[8];
      *(float4*)&av[0] = *(const float4*)&At[k][ty * 4];
      *(float4*)&av[4] = *(const float4*)&At[k][ty * 4 + 64];
      *(float4*)&bv[0] = *(const float4*)&Bs[k][tx * 4];
      *(float4*)&bv[4] = *(const float4*)&Bs[k][tx * 4 + 64];
#pragma unroll
      for (int i = 0; i < 8; ++i)
#pragma unroll
        for (int j = 0; j < 8; ++j) acc[i][j] = fmaf(av[i], bv[j], acc[i][j]);
    }
  }
#pragma unroll
  for (int ih = 0; ih < 2; ++ih)
#pragma unroll
  for (int i2 = 0; i2 < 4; ++i2) {
    int i = ih * 4 + i2;
    int m = m0 + ty * 4 + i2 + ih * 64;
#pragma unroll
    for (int jh = 0; jh < 2; ++jh) {
      int cb = n0 + jh * 64 + tx * 4;
      float o[4];
#pragma unroll
      for (int j2 = 0; j2 < 4; ++j2) {
        float x = acc[i][jh*4+j2] + bias[cb + j2];
        o[j2] = doRelu ? fmaxf(x, 0.f) : x;
      }
      *(float4*)(C + (size_t)m * N + cb) = *(float4*)&o[0];
    }
  }
}

// ---------- final fc (128->13) + log_softmax ----------
__global__ __launch_bounds__(256) void final_k(const float* __restrict__ H, const float* __restrict__ W4,
                        const float* __restrict__ B4, float* __restrict__ O, int rows) {
  __shared__ float w4s[128 * 13];
  __shared__ float b4s[13];
  int tid = threadIdx.x;
  for (int i = tid; i < 1664; i += 256) w4s[i] = W4[i];
  if (tid < 13) b4s[tid] = B4[tid];
  __syncthreads();
  int r = blockIdx.x * 256 + tid;
  if (r >= rows) return;
  const float* h = H + (size_t)r * 128;
  float l[13];
#pragma unroll
  for (int c = 0; c < 13; ++c) l[c] = b4s[c];
  for (int k4 = 0; k4 < 32; ++k4) {
    float4 hv = *(const float4*)(h + k4 * 4);
#pragma unroll
    for (int q = 0; q < 4; ++q) {
      float x = (q == 0) ? hv.x : (q == 1) ? hv.y : (q == 2) ? hv.z : hv.w;
      int k = k4 * 4 + q;
#pragma unroll
      for (int c = 0; c < 13; ++c) l[c] = fmaf(x, w4s[k * 13 + c], l[c]);
    }
  }
  float mx = l[0];
#pragma unroll
  for (int c = 1; c < 13; ++c) mx = fmaxf(mx, l[c]);
  float s = 0.f;
#pragma unroll
  for (int c = 0; c < 13; ++c) s += expf(l[c] - mx);
  float lse = mx + logf(s);
  float* op = O + (size_t)r * 13;
#pragma unroll
  for (int c = 0; c < 13; ++c) op[c] = l[c] - lse;
}

extern "C" void kernel_launch(void* const* d_in, const int* in_sizes, int n_in,
                              void* d_out, int out_size, void* d_ws, size_t ws_size,
                              hipStream_t stream) {
  const float* P = (const float*)d_in[0];
  const float* W1s[3] = {(const float*)d_in[1], (const float*)d_in[5], (const float*)d_in[9]};
  const float* B1s[3] = {(const float*)d_in[2], (const float*)d_in[6], (const float*)d_in[10]};
  const float* W2s_[3] = {(const float*)d_in[3], (const float*)d_in[7], (const float*)d_in[11]};
  const float* B2s[3] = {(const float*)d_in[4], (const float*)d_in[8], (const float*)d_in[12]};
  const float* MW1 = (const float*)d_in[13]; const float* MB1 = (const float*)d_in[14];
  const float* MW2 = (const float*)d_in[15]; const float* MB2 = (const float*)d_in[16];
  const float* MW3 = (const float*)d_in[17]; const float* MB3 = (const float*)d_in[18];
  const float* MW4 = (const float*)d_in[19]; const float* MB4 = (const float*)d_in[20];

  char* w = (char*)d_ws;
  float* F   = (float*)(w + 0);            // 32768 x 192            [0,   25165824)
  float* S   = (float*)(w + 25165824);     // 32768                  [.., 25296896)
  float* U   = (float*)(w + 25296896);     // 32768 x 64             [.., 33685504)
  float* V   = (float*)(w + 33685504);     // 32768 x 64             [.., 42074112)
  int*   IDX = (int*)  (w + 42074112);     // 32768 x 30             [.., 46006272)
  float* D   = (float*)(w + 46006272);     // big: 8192 x 4096 (134MB) / small: 2048 x 4096
  (void)in_sizes; (void)n_in; (void)out_size;

  bool bigWS = (ws_size >= 213778432u);

  for (int l = 0; l < 3; ++l) {
    const float* X = (l == 0) ? P : (F + (l - 1) * 64);
    int rs = (l == 0) ? 6 : 192;
    int C  = (l == 0) ? 6 : 64;
    norms_k<<<TOTAL / 256, 256, 0, stream>>>(X, rs, C, S);
    if (bigWS) {
      for (int g = 0; g < 4; ++g) {        // 8192 rows (2 batches) per pair
        dist_k<<<dim3(32, 64), 256, 0, stream>>>(X, rs, C, S, g * 8192, D);
        topk_k<<<8192, 64, 0, stream>>>(D, IDX, g * 8192);
      }
    } else {
      for (int g = 0; g < 16; ++g) {       // 2048-row strips
        dist_k<<<dim3(32, 16), 256, 0, stream>>>(X, rs, C, S, g * 2048, D);
        topk_k<<<2048, 64, 0, stream>>>(D, IDX, g * 2048);
      }
    }
    uv_k<<<TOTAL / 4, 256, 0, stream>>>(X, rs, C, W1s[l], B1s[l], U, V);
    edge_k<<<TOTAL / 8, 256, 0, stream>>>(U, V, W2s_[l], B2s[l], IDX, F, l * 64);
  }

  float* OUT = (float*)d_out;
  if (bigWS) {
    float* T1 = (float*)(w + 46006272);      // 32768 x 1024 (alias D)
    float* T2 = (float*)(w + 180224000);     // 32768 x 256
    float* T3 = (float*)(w + 25296896);      // 32768 x 128  (alias U+V)
    gemm_k<<<dim3(8, 256), 256, 0, stream>>>(F, MW1, MB1, T1, 32768, 1024, 192, 192, 1);
    gemm_k<<<dim3(2, 256), 256, 0, stream>>>(T1, MW2, MB2, T2, 32768, 256, 1024, 1024, 1);
    gemm_k<<<dim3(1, 256), 256, 0, stream>>>(T2, MW3, MB3, T3, 32768, 128, 256, 256, 1);
    final_k<<<128, 256, 0, stream>>>(T3, MW4, MB4, OUT, 32768);
  } else {
    float* T1 = D;
    float* T2 = U;
    float* T3 = V;
    for (int ch = 0; ch < 4; ++ch) {
      const float* A0 = F + (size_t)ch * 8192 * 192;
      gemm_k<<<dim3(8, 64), 256, 0, stream>>>(A0, MW1, MB1, T1, 8192, 1024, 192, 192, 1);
      gemm_k<<<dim3(2, 64), 256, 0, stream>>>(T1, MW2, MB2, T2, 8192, 256, 1024, 1024, 1);
      gemm_k<<<dim3(1, 64), 256, 0, stream>>>(T2, MW3, MB3, T3, 8192, 128, 256, 256, 1);
      final_k<<<8192 / 256, 256, 0, stream>>>(T3, MW4, MB4, OUT + (size_t)ch * 8192 * 13, 8192);
    }
  }
}

// Round 12
// 3027.263 us; speedup vs baseline: 1.7606x; 1.0683x over previous
//
#include <hip/hip_runtime.h>
#include <math.h>

#define NPTS 4096
#define NBATCH 8
#define TOTAL (NBATCH*NPTS)   // 32768
#define KNN 30

typedef __attribute__((ext_vector_type(8))) __bf16 bf16x8;
typedef __attribute__((ext_vector_type(4))) float f32x4;

// ---------- helpers ----------
__device__ __forceinline__ unsigned key_xform(float v) {
  unsigned u = __float_as_uint(v);
  return (u & 0x80000000u) ? ~u : (u | 0x80000000u);  // monotonic float->uint
}
__device__ __forceinline__ float key_unxform(unsigned k) {
  unsigned u = (k & 0x80000000u) ? (k ^ 0x80000000u) : ~k;
  return __uint_as_float(u);
}
__device__ __forceinline__ unsigned short bf16_rne(float x) {
  unsigned u = __float_as_uint(x);
  return (unsigned short)((u + 0x7FFFu + ((u >> 16) & 1u)) >> 16);
}

// ---------- row squared-norms ----------
__global__ void norms_k(const float* __restrict__ X, int rs, int C, float* __restrict__ S) {
  int i = blockIdx.x * 256 + threadIdx.x;
  if (i >= TOTAL) return;
  const float* r = X + (size_t)i * rs;
  float a = 0.f;
  if ((C & 3) == 0) {
    for (int c4 = 0; c4 < (C >> 2); ++c4) {
      float4 v = *(const float4*)(r + c4 * 4);
      a = fmaf(v.x, v.x, a); a = fmaf(v.y, v.y, a);
      a = fmaf(v.z, v.z, a); a = fmaf(v.w, v.w, a);
    }
  } else {
    for (int c = 0; c < C; ++c) { float v = r[c]; a = fmaf(v, v, a); }
  }
  S[i] = a;
}

// ---------- distance tile GEMM: D[localRow][j] = s_i + s_j - 2*dot ----------
__global__ __launch_bounds__(256) void dist_k(const float* __restrict__ X, int rs, int C,
    const float* __restrict__ S, int rowBase, float* __restrict__ D) {
  __shared__ __align__(16) float At[64][128];
  __shared__ __align__(16) float Bt[64][128];
  __shared__ float sA[128], sB[128];
  int tid = threadIdx.x;
  int bx = blockIdx.x, by = blockIdx.y;
  int gr0 = rowBase + by * 128;
  int batch0 = gr0 >> 12;
  int a0 = gr0;
  int b0 = (batch0 << 12) + bx * 128;
  if (tid < 128) sA[tid] = S[a0 + tid];
  else           sB[tid - 128] = S[b0 + tid - 128];
  if ((C & 3) == 0) {
    int nv = 128 * (C >> 2);
    for (int i = tid; i < nv; i += 256) {
      int m = i & 127, kq = i >> 7;
      float4 va = *(const float4*)(X + (size_t)(a0 + m) * rs + kq * 4);
      At[kq*4+0][m] = va.x; At[kq*4+1][m] = va.y; At[kq*4+2][m] = va.z; At[kq*4+3][m] = va.w;
      float4 vb = *(const float4*)(X + (size_t)(b0 + m) * rs + kq * 4);
      Bt[kq*4+0][m] = vb.x; Bt[kq*4+1][m] = vb.y; Bt[kq*4+2][m] = vb.z; Bt[kq*4+3][m] = vb.w;
    }
  } else {
    for (int i = tid; i < 128 * C; i += 256) {
      int m = i & 127, k = i >> 7;
      At[k][m] = X[(size_t)(a0 + m) * rs + k];
      Bt[k][m] = X[(size_t)(b0 + m) * rs + k];
    }
  }
  __syncthreads();
  float acc[8][8] = {};
  int tx = tid & 15, ty = tid >> 4;
  for (int k = 0; k < C; ++k) {
    float av[8], bv[8];
    *(float4*)&av[0] = *(const float4*)&At[k][ty * 4];
    *(float4*)&av[4] = *(const float4*)&At[k][ty * 4 + 64];
    *(float4*)&bv[0] = *(const float4*)&Bt[k][tx * 4];
    *(float4*)&bv[4] = *(const float4*)&Bt[k][tx * 4 + 64];
#pragma unroll
    for (int i = 0; i < 8; ++i)
#pragma unroll
      for (int j = 0; j < 8; ++j) acc[i][j] = fmaf(av[i], bv[j], acc[i][j]);
  }
#pragma unroll
  for (int ih = 0; ih < 2; ++ih)
#pragma unroll
  for (int i2 = 0; i2 < 4; ++i2) {
    int i = ih * 4 + i2;
    int row = ty * 4 + i2 + ih * 64;
    int lr = by * 128 + row;
    float si = sA[row];
#pragma unroll
    for (int jh = 0; jh < 2; ++jh) {
      int cb = jh * 64 + tx * 4;
      float4 o;
      o.x = si + sB[cb+0] - 2.f * acc[i][jh*4+0];
      o.y = si + sB[cb+1] - 2.f * acc[i][jh*4+1];
      o.z = si + sB[cb+2] - 2.f * acc[i][jh*4+2];
      o.w = si + sB[cb+3] - 2.f * acc[i][jh*4+3];
      *(float4*)(D + (size_t)lr * NPTS + bx * 128 + cb) = o;
    }
  }
}

// ---------- top-30 smallest per row: register-resident, 1 wave per row ----------
#define SENTK 0xFFFFFFFFFFFFFFFFull
__global__ __launch_bounds__(64) void topk_k(const float* __restrict__ D, int* __restrict__ IDXo,
                                             int rowBase) {
  int lane = threadIdx.x;
  int gr = rowBase + blockIdx.x;
  int bBase = gr & ~(NPTS - 1);
  const float* drow = D + (size_t)blockIdx.x * NPTS;
  float4 dv[16];
#pragma unroll
  for (int q = 0; q < 16; ++q) dv[q] = ((const float4*)drow)[lane + 64 * q];
  unsigned long long k1 = SENTK, k2 = SENTK;
#pragma unroll
  for (int q = 0; q < 16; ++q) {
#pragma unroll
    for (int r = 0; r < 4; ++r) {
      float d = (r == 0) ? dv[q].x : (r == 1) ? dv[q].y : (r == 2) ? dv[q].z : dv[q].w;
      unsigned idx = 4u * (lane + 64u * q) + r;
      unsigned long long kk = ((unsigned long long)key_xform(d) << 32) | idx;
      if (kk < k1) { k2 = k1; k1 = kk; } else if (kk < k2) k2 = kk;
    }
  }
  for (int it = 0; it < KNN; ++it) {
    unsigned long long km = k1;
#pragma unroll
    for (int d = 1; d < 64; d <<= 1) {
      unsigned long long o = __shfl_xor(km, d);
      if (o < km) km = o;
    }
    unsigned widx = (unsigned)(km & 0xFFFFFFFFu);
    if (lane == 0) IDXo[(size_t)gr * KNN + it] = bBase + (int)widx;
    if (((widx >> 2) & 63u) == (unsigned)lane) {
      if (k2 != SENTK) { k1 = k2; k2 = SENTK; }
      else {
        k1 = SENTK; k2 = SENTK;
#pragma unroll
        for (int q = 0; q < 16; ++q) {
#pragma unroll
          for (int r = 0; r < 4; ++r) {
            float d = (r == 0) ? dv[q].x : (r == 1) ? dv[q].y : (r == 2) ? dv[q].z : dv[q].w;
            unsigned idx = 4u * (lane + 64u * q) + r;
            unsigned long long kk = ((unsigned long long)key_xform(d) << 32) | idx;
            if (kk > km) {
              if (kk < k1) { k2 = k1; k1 = kk; } else if (kk < k2) k2 = kk;
            }
          }
        }
      }
    }
  }
}

// ---------- per-point u/v: u = X@(W1a-W1b)+b1, v = X@W1b ----------
__global__ __launch_bounds__(256) void uv_k(const float* __restrict__ X, int rs, int C,
    const float* __restrict__ W1, const float* __restrict__ B1,
    float* __restrict__ U, float* __restrict__ V) {
  __shared__ float wd[64][64];
  __shared__ float wb[64][64];
  __shared__ float xs[4][64];
  int tid = threadIdx.x;
  int c = tid & 63, pl = tid >> 6;
  for (int i = tid; i < C * 64; i += 256) {
    float a = W1[i], b = W1[C * 64 + i];
    wd[i >> 6][i & 63] = a - b;
    wb[i >> 6][i & 63] = b;
  }
  int p0 = blockIdx.x * 4;
  for (int i = tid; i < 4 * C; i += 256)
    xs[i / C][i % C] = X[(size_t)(p0 + i / C) * rs + (i % C)];
  __syncthreads();
  float u = B1[c], v = 0.f;
  for (int k = 0; k < C; ++k) {
    float x = xs[pl][k];
    u = fmaf(x, wd[k][c], u);
    v = fmaf(x, wb[k][c], v);
  }
  int p = p0 + pl;
  U[(size_t)p * 64 + c] = u;
  V[(size_t)p * 64 + c] = v;
}

// ---------- edge conv: F[p][colOut+c] = max_j relu(u_p + v_idx)@W2 + b2 ----------
__global__ __launch_bounds__(256) void edge_k(const float* __restrict__ U, const float* __restrict__ V,
    const float* __restrict__ W2, const float* __restrict__ B2, const int* __restrict__ IDX,
    float* __restrict__ F, int colOut) {
  __shared__ __align__(16) float At[16][260];
  __shared__ __align__(16) float W2s[64][64];
  __shared__ __align__(16) float us[8][64];
  __shared__ int idxs[256];
  __shared__ unsigned om[512];
  int tid = threadIdx.x;
  int p0 = blockIdx.x * 8;
  for (int i = tid; i < 1024; i += 256) ((float4*)W2s)[i] = ((const float4*)W2)[i];
  for (int i = tid; i < 128; i += 256)
    ((float4*)us)[i] = ((const float4*)(U + (size_t)p0 * 64))[i];
  for (int m = tid; m < 256; m += 256)
    idxs[m] = IDX[(size_t)p0 * KNN + (m < 240 ? m : 239)];
  for (int i = tid; i < 512; i += 256) om[i] = 0u;
  __syncthreads();
  float acc[8][8] = {};
  int tx = tid & 7, ty = tid >> 3;
  for (int kc = 0; kc < 4; ++kc) {
    for (int i = tid; i < 1024; i += 256) {
      int m = i >> 2, kq = i & 3;
      int um = m / 30; if (um > 7) um = 7;
      float4 vv = *(const float4*)(V + (size_t)idxs[m] * 64 + kc * 16 + kq * 4);
      float4 uu = *(const float4*)&us[um][kc * 16 + kq * 4];
      At[kq*4+0][m] = fmaxf(uu.x + vv.x, 0.f);
      At[kq*4+1][m] = fmaxf(uu.y + vv.y, 0.f);
      At[kq*4+2][m] = fmaxf(uu.z + vv.z, 0.f);
      At[kq*4+3][m] = fmaxf(uu.w + vv.w, 0.f);
    }
    __syncthreads();
#pragma unroll
    for (int k = 0; k < 16; ++k) {
      float av[8], bv[8];
      *(float4*)&av[0] = *(const float4*)&At[k][ty * 4];
      *(float4*)&av[4] = *(const float4*)&At[k][ty * 4 + 128];
      *(float4*)&bv[0] = *(const float4*)&W2s[kc * 16 + k][tx * 4];
      *(float4*)&bv[4] = *(const float4*)&W2s[kc * 16 + k][tx * 4 + 32];
#pragma unroll
      for (int i = 0; i < 8; ++i)
#pragma unroll
        for (int j = 0; j < 8; ++j) acc[i][j] = fmaf(av[i], bv[j], acc[i][j]);
    }
    __syncthreads();
  }
#pragma unroll
  for (int ih = 0; ih < 2; ++ih) {
    int mbase = ty * 4 + ih * 128;
    if (mbase >= 240) continue;
    int ptA = mbase / 30;
    int ptB = (mbase + 3) / 30;
    int split = (ptB > ptA) ? (ptB * 30 - mbase) : 4;
    float mx[8];
#pragma unroll
    for (int j = 0; j < 8; ++j) mx[j] = acc[ih*4+0][j];
#pragma unroll
    for (int i2 = 1; i2 < 4; ++i2) {
      bool flushNow = (i2 == split);
      if (flushNow) {
#pragma unroll
        for (int j = 0; j < 8; ++j)
          atomicMax(&om[ptA * 64 + tx * 4 + (j & 3) + (j >> 2) * 32], key_xform(mx[j]));
#pragma unroll
        for (int j = 0; j < 8; ++j) mx[j] = acc[ih*4+i2][j];
      } else {
#pragma unroll
        for (int j = 0; j < 8; ++j) mx[j] = fmaxf(mx[j], acc[ih*4+i2][j]);
      }
    }
    int ptEnd = (split == 4) ? ptA : ptB;
#pragma unroll
    for (int j = 0; j < 8; ++j)
      atomicMax(&om[ptEnd * 64 + tx * 4 + (j & 3) + (j >> 2) * 32], key_xform(mx[j]));
  }
  __syncthreads();
  for (int i = tid; i < 512; i += 256) {
    int pt = i >> 6, c = i & 63;
    F[(size_t)(p0 + pt) * 192 + colOut + c] = key_unxform(om[i]) + B2[c];
  }
}

// ---------- generic fp32 GEMM (fallback path only) ----------
__global__ __launch_bounds__(256) void gemm_k(const float* __restrict__ A, const float* __restrict__ B,
    const float* __restrict__ bias, float* __restrict__ C, int M, int N, int Kd, int lda, int doRelu) {
  __shared__ __align__(16) float At[16][128];
  __shared__ __align__(16) float Bs[16][128];
  int tid = threadIdx.x, bx = blockIdx.x, by = blockIdx.y;
  int m0 = by * 128, n0 = bx * 128;
  float acc[8][8] = {};
  int tx = tid & 15, ty = tid >> 4;
  for (int k0 = 0; k0 < Kd; k0 += 16) {
    if (k0) __syncthreads();
    for (int i = tid; i < 512; i += 256) {
      int m = i & 127, kq = i >> 7;
      float4 v = *(const float4*)(A + (size_t)(m0 + m) * lda + k0 + kq * 4);
      At[kq*4+0][m] = v.x; At[kq*4+1][m] = v.y; At[kq*4+2][m] = v.z; At[kq*4+3][m] = v.w;
    }
    for (int i = tid; i < 512; i += 256) {
      int n4 = i & 31, k = i >> 5;
      *(float4*)&Bs[k][n4 * 4] = *(const float4*)(B + (size_t)(k0 + k) * N + n0 + n4 * 4);
    }
    __syncthreads();
#pragma unroll
    for (int k = 0; k < 16; ++k) {
      float av[8], bv[8];
      *(float4*)&av[0] = *(const float4*)&At[k][ty * 4];
      *(float4*)&av[4] = *(const float4*)&At[k][ty * 4 + 64];
      *(float4*)&bv[0] = *(const float4*)&Bs[k][tx * 4];
      *(float4*)&bv[4] = *(const float4*)&Bs[k][tx * 4 + 64];
#pragma unroll
      for (int i = 0; i < 8; ++i)
#pragma unroll
        for (int j = 0; j < 8; ++j) acc[i][j] = fmaf(av[i], bv[j], acc[i][j]);
    }
  }
#pragma unroll
  for (int ih = 0; ih < 2; ++ih)
#pragma unroll
  for (int i2 = 0; i2 < 4; ++i2) {
    int i = ih * 4 + i2;
    int m = m0 + ty * 4 + i2 + ih * 64;
#pragma unroll
    for (int jh = 0; jh < 2; ++jh) {
      int cb = n0 + jh * 64 + tx * 4;
      float o[4];
#pragma unroll
      for (int j2 = 0; j2 < 4; ++j2) {
        float x = acc[i][jh*4+j2] + bias[cb + j2];
        o[j2] = doRelu ? fmaxf(x, 0.f) : x;
      }
      *(float4*)(C + (size_t)m * N + cb) = *(float4*)&o[0];
    }
  }
}

// ---------- pack weight W (Kd x N, row-major) into split-bf16 fragment layout ----------
// dst element ((n>>4)*(Kd>>3) + (k>>3))*128 + (n&15)*8 + (k&7)
__global__ void packw_k(const float* __restrict__ W, int Kd, int N,
                        unsigned short* __restrict__ Ph, unsigned short* __restrict__ Pl) {
  int i = blockIdx.x * 256 + threadIdx.x;
  if (i >= Kd * N) return;
  int k = i / N, n = i % N;
  float w = W[i];
  unsigned short hb = bf16_rne(w);
  unsigned short lb = bf16_rne(w - __uint_as_float((unsigned)hb << 16));
  size_t dst = ((size_t)(n >> 4) * (Kd >> 3) + (k >> 3)) * 128 + (size_t)(n & 15) * 8 + (k & 7);
  Ph[dst] = hb; Pl[dst] = lb;
}

// ---------- split-bf16 MFMA GEMM: C = relu?(A @ W + bias), 128x128 tile ----------
// A fp32 row-major (lda); W pre-packed split-bf16 fragment layout; Kd % 32 == 0
__global__ __launch_bounds__(256) void gemm_mfma_k(const float* __restrict__ A,
    const unsigned short* __restrict__ Bh, const unsigned short* __restrict__ Bl,
    const float* __restrict__ bias, float* __restrict__ C,
    int N, int Kd, int lda, int doRelu) {
  __shared__ __align__(16) unsigned short Ash[4096], Asl[4096], Bsh[4096], Bsl[4096];
  int tid = threadIdx.x;
  int bx = blockIdx.x, by = blockIdx.y;
  int m0 = by * 128, n0 = bx * 128;
  int wid = tid >> 6, lane = tid & 63;
  int mw = (wid >> 1) * 64, nw = (wid & 1) * 64;   // wave's 64x64 sub-tile
  int Kb = Kd >> 3;
  f32x4 acc[4][4] = {};
  for (int k0 = 0; k0 < Kd; k0 += 32) {
    if (k0) __syncthreads();
    // stage A: fp32 -> split bf16, fragment-linear [mt][kg][m16][j]
    for (int s = tid; s < 1024; s += 256) {
      int m = s >> 3, q = s & 7;
      float4 v = *(const float4*)(A + (size_t)(m0 + m) * lda + k0 + q * 4);
      unsigned short h0 = bf16_rne(v.x), h1 = bf16_rne(v.y), h2 = bf16_rne(v.z), h3 = bf16_rne(v.w);
      unsigned short l0 = bf16_rne(v.x - __uint_as_float((unsigned)h0 << 16));
      unsigned short l1 = bf16_rne(v.y - __uint_as_float((unsigned)h1 << 16));
      unsigned short l2 = bf16_rne(v.z - __uint_as_float((unsigned)h2 << 16));
      unsigned short l3 = bf16_rne(v.w - __uint_as_float((unsigned)h3 << 16));
      int eo = (((m >> 4) * 4 + (q >> 1)) * 16 + (m & 15)) * 8 + (q & 1) * 4;
      ushort4 hv; hv.x = h0; hv.y = h1; hv.z = h2; hv.w = h3;
      ushort4 lv; lv.x = l0; lv.y = l1; lv.z = l2; lv.w = l3;
      *(ushort4*)(Ash + eo) = hv;
      *(ushort4*)(Asl + eo) = lv;
    }
    // stage B: copy pre-packed chunks (16B units)
    for (int s = tid; s < 1024; s += 256) {
      int p = s >> 9, r = s & 511;
      int nt = r >> 6, kk = r & 63;
      int kg = kk >> 4, u = kk & 15;
      size_t src = ((size_t)((n0 >> 4) + nt) * Kb + (k0 >> 3) + kg) * 16 + u;
      uint4 val = p ? ((const uint4*)Bl)[src] : ((const uint4*)Bh)[src];
      ((uint4*)(p ? Bsl : Bsh))[(nt * 4 + kg) * 16 + u] = val;
    }
    __syncthreads();
    bf16x8 ah[4], al[4], bhf[4], blf[4];
#pragma unroll
    for (int t = 0; t < 4; ++t) {
      int ao = ((mw >> 4) + t) * 1024 + lane * 16;
      int bo = ((nw >> 4) + t) * 1024 + lane * 16;
      ah[t]  = *(const bf16x8*)((const char*)Ash + ao);
      al[t]  = *(const bf16x8*)((const char*)Asl + ao);
      bhf[t] = *(const bf16x8*)((const char*)Bsh + bo);
      blf[t] = *(const bf16x8*)((const char*)Bsl + bo);
    }
#pragma unroll
    for (int mt = 0; mt < 4; ++mt)
#pragma unroll
      for (int nt = 0; nt < 4; ++nt) {
        acc[mt][nt] = __builtin_amdgcn_mfma_f32_16x16x32_bf16(ah[mt], bhf[nt], acc[mt][nt], 0, 0, 0);
        acc[mt][nt] = __builtin_amdgcn_mfma_f32_16x16x32_bf16(ah[mt], blf[nt], acc[mt][nt], 0, 0, 0);
        acc[mt][nt] = __builtin_amdgcn_mfma_f32_16x16x32_bf16(al[mt], bhf[nt], acc[mt][nt], 0, 0, 0);
      }
  }
  // epilogue: lane holds C[row=(lane>>4)*4+r][col=lane&15] per 16x16 tile
#pragma unroll
  for (int nt = 0; nt < 4; ++nt) {
    int col = n0 + nw + nt * 16 + (lane & 15);
    float b = bias[col];
#pragma unroll
    for (int mt = 0; mt < 4; ++mt) {
      int rbase = m0 + mw + mt * 16 + ((lane >> 4) << 2);
#pragma unroll
      for (int r = 0; r < 4; ++r) {
        float x = acc[mt][nt][r] + b;
        if (doRelu) x = fmaxf(x, 0.f);
        C[(size_t)(rbase + r) * N + col] = x;
      }
    }
  }
}

// ---------- final fc (128->13) + log_softmax ----------
__global__ __launch_bounds__(256) void final_k(const float* __restrict__ H, const float* __restrict__ W4,
                        const float* __restrict__ B4, float* __restrict__ O, int rows) {
  __shared__ float w4s[128 * 13];
  __shared__ float b4s[13];
  int tid = threadIdx.x;
  for (int i = tid; i < 1664; i += 256) w4s[i] = W4[i];
  if (tid < 13) b4s[tid] = B4[tid];
  __syncthreads();
  int r = blockIdx.x * 256 + tid;
  if (r >= rows) return;
  const float* h = H + (size_t)r * 128;
  float l[13];
#pragma unroll
  for (int c = 0; c < 13; ++c) l[c] = b4s[c];
  for (int k4 = 0; k4 < 32; ++k4) {
    float4 hv = *(const float4*)(h + k4 * 4);
#pragma unroll
    for (int q = 0; q < 4; ++q) {
      float x = (q == 0) ? hv.x : (q == 1) ? hv.y : (q == 2) ? hv.z : hv.w;
      int k = k4 * 4 + q;
#pragma unroll
      for (int c = 0; c < 13; ++c) l[c] = fmaf(x, w4s[k * 13 + c], l[c]);
    }
  }
  float mx = l[0];
#pragma unroll
  for (int c = 1; c < 13; ++c) mx = fmaxf(mx, l[c]);
  float s = 0.f;
#pragma unroll
  for (int c = 0; c < 13; ++c) s += expf(l[c] - mx);
  float lse = mx + logf(s);
  float* op = O + (size_t)r * 13;
#pragma unroll
  for (int c = 0; c < 13; ++c) op[c] = l[c] - lse;
}

extern "C" void kernel_launch(void* const* d_in, const int* in_sizes, int n_in,
                              void* d_out, int out_size, void* d_ws, size_t ws_size,
                              hipStream_t stream) {
  const float* P = (const float*)d_in[0];
  const float* W1s[3] = {(const float*)d_in[1], (const float*)d_in[5], (const float*)d_in[9]};
  const float* B1s[3] = {(const float*)d_in[2], (const float*)d_in[6], (const float*)d_in[10]};
  const float* W2s_[3] = {(const float*)d_in[3], (const float*)d_in[7], (const float*)d_in[11]};
  const float* B2s[3] = {(const float*)d_in[4], (const float*)d_in[8], (const float*)d_in[12]};
  const float* MW1 = (const float*)d_in[13]; const float* MB1 = (const float*)d_in[14];
  const float* MW2 = (const float*)d_in[15]; const float* MB2 = (const float*)d_in[16];
  const float* MW3 = (const float*)d_in[17]; const float* MB3 = (const float*)d_in[18];
  const float* MW4 = (const float*)d_in[19]; const float* MB4 = (const float*)d_in[20];

  char* w = (char*)d_ws;
  float* F   = (float*)(w + 0);            // 32768 x 192            [0,   25165824)
  float* S   = (float*)(w + 25165824);     // 32768                  [.., 25296896)
  float* U   = (float*)(w + 25296896);     // 32768 x 64             [.., 33685504)
  float* V   = (float*)(w + 33685504);     // 32768 x 64             [.., 42074112)
  int*   IDX = (int*)  (w + 42074112);     // 32768 x 30             [.., 46006272)
  float* D   = (float*)(w + 46006272);     // big: 8192 x 4096 (134MB) / small: 2048 x 4096
  (void)in_sizes; (void)n_in; (void)out_size;

  bool bigWS = (ws_size >= 213778432u);

  for (int l = 0; l < 3; ++l) {
    const float* X = (l == 0) ? P : (F + (l - 1) * 64);
    int rs = (l == 0) ? 6 : 192;
    int C  = (l == 0) ? 6 : 64;
    norms_k<<<TOTAL / 256, 256, 0, stream>>>(X, rs, C, S);
    if (bigWS) {
      for (int g = 0; g < 4; ++g) {
        dist_k<<<dim3(32, 64), 256, 0, stream>>>(X, rs, C, S, g * 8192, D);
        topk_k<<<8192, 64, 0, stream>>>(D, IDX, g * 8192);
      }
    } else {
      for (int g = 0; g < 16; ++g) {
        dist_k<<<dim3(32, 16), 256, 0, stream>>>(X, rs, C, S, g * 2048, D);
        topk_k<<<2048, 64, 0, stream>>>(D, IDX, g * 2048);
      }
    }
    uv_k<<<TOTAL / 4, 256, 0, stream>>>(X, rs, C, W1s[l], B1s[l], U, V);
    edge_k<<<TOTAL / 8, 256, 0, stream>>>(U, V, W2s_[l], B2s[l], IDX, F, l * 64);
  }

  float* OUT = (float*)d_out;
  if (bigWS) {
    float* T1 = (float*)(w + 46006272);      // 32768 x 1024 (alias D)
    float* T2 = (float*)(w + 180224000);     // 32768 x 256
    float* T3 = (float*)(w + 25296896);      // 32768 x 128  (alias U+V)
    // packed weights alias IDX region (dead after last edge_k): 1.92MB < 3.93MB
    unsigned short* PW1h = (unsigned short*)(w + 42074112);
    unsigned short* PW1l = (unsigned short*)(w + 42467328);
    unsigned short* PW2h = (unsigned short*)(w + 42860544);
    unsigned short* PW2l = (unsigned short*)(w + 43384832);
    unsigned short* PW3h = (unsigned short*)(w + 43909120);
    unsigned short* PW3l = (unsigned short*)(w + 43974656);
    packw_k<<<(192 * 1024) / 256, 256, 0, stream>>>(MW1, 192, 1024, PW1h, PW1l);
    packw_k<<<(1024 * 256) / 256, 256, 0, stream>>>(MW2, 1024, 256, PW2h, PW2l);
    packw_k<<<(256 * 128) / 256, 256, 0, stream>>>(MW3, 256, 128, PW3h, PW3l);
    gemm_mfma_k<<<dim3(8, 256), 256, 0, stream>>>(F,  PW1h, PW1l, MB1, T1, 1024, 192, 192, 1);
    gemm_mfma_k<<<dim3(2, 256), 256, 0, stream>>>(T1, PW2h, PW2l, MB2, T2, 256, 1024, 1024, 1);
    gemm_mfma_k<<<dim3(1, 256), 256, 0, stream>>>(T2, PW3h, PW3l, MB3, T3, 128, 256, 256, 1);
    final_k<<<128, 256, 0, stream>>>(T3, MW4, MB4, OUT, 32768);
  } else {
    float* T1 = D;
    float* T2 = U;
    float* T3 = V;
    for (int ch = 0; ch < 4; ++ch) {
      const float* A0 = F + (size_t)ch * 8192 * 192;
      gemm_k<<<dim3(8, 64), 256, 0, stream>>>(A0, MW1, MB1, T1, 8192, 1024, 192, 192, 1);
      gemm_k<<<dim3(2, 64), 256, 0, stream>>>(T1, MW2, MB2, T2, 8192, 256, 1024, 1024, 1);
      gemm_k<<<dim3(1, 64), 256, 0, stream>>>(T2, MW3, MB3, T3, 8192, 128, 256, 256, 1);
      final_k<<<8192 / 256, 256, 0, stream>>>(T3, MW4, MB4, OUT + (size_t)ch * 8192 * 13, 8192);
    }
  }
}